// Round 12
// baseline (373.254 us; speedup 1.0000x reference)
//
#include <hip/hip_runtime.h>
#include <hip/hip_fp16.h>
#include <math.h>

#define NODES 100000
#define EDGES 1250000
#define HD 64
#define NFD 16
#define CHUNK 1024
#define NCHUNK ((NODES + CHUNK - 1) / CHUNK)
#define BN_INV 0.9999950000374996f  // 1/sqrt(1+1e-5)
#define LP 65  // LDS row pitch: 65 % 32 == 1 -> 2-way bank aliasing (free)

// ---------------- graph build ----------------

__global__ void k_hist(const int* __restrict__ ei, int* __restrict__ deg) {
  int e = blockIdx.x * blockDim.x + threadIdx.x;
  if (e < EDGES) atomicAdd(&deg[ei[EDGES + e]], 1);
}

__global__ void k_scan1(const int* __restrict__ deg, int* __restrict__ part) {
  __shared__ int lds[256];
  int t = threadIdx.x, b = blockIdx.x;
  int base = b * CHUNK + t * 4;
  int s = 0;
#pragma unroll
  for (int m = 0; m < 4; m++) { int i = base + m; if (i < NODES) s += deg[i]; }
  lds[t] = s; __syncthreads();
  for (int off = 128; off > 0; off >>= 1) {
    if (t < off) lds[t] += lds[t + off];
    __syncthreads();
  }
  if (t == 0) part[b] = lds[0];
}

__global__ void k_scan2(int* __restrict__ part) {
  if (threadIdx.x == 0 && blockIdx.x == 0) {
    int run = 0;
    for (int c = 0; c < NCHUNK; c++) { int v = part[c]; part[c] = run; run += v; }
  }
}

__global__ void k_scan3(const int* __restrict__ deg, const int* __restrict__ part,
                        int* __restrict__ rowptr, int* __restrict__ cur,
                        float* __restrict__ dis) {
  __shared__ int lds[256];
  int t = threadIdx.x, b = blockIdx.x;
  int base = b * CHUNK + t * 4;
  int dl[4]; int s = 0;
#pragma unroll
  for (int m = 0; m < 4; m++) { int i = base + m; dl[m] = (i < NODES) ? deg[i] : 0; s += dl[m]; }
  lds[t] = s; __syncthreads();
  for (int off = 1; off < 256; off <<= 1) {
    int add = (t >= off) ? lds[t - off] : 0;
    __syncthreads();
    lds[t] += add;
    __syncthreads();
  }
  int run = part[b] + lds[t] - s;  // exclusive prefix for this thread
#pragma unroll
  for (int m = 0; m < 4; m++) {
    int i = base + m;
    if (i < NODES) {
      rowptr[i] = run; cur[i] = run;
      dis[i] = 1.0f / sqrtf((float)(dl[m] + 1));  // GCN: indeg + self-loop
    }
    run += dl[m];
  }
  if (b == 0 && t == 0) rowptr[NODES] = EDGES;
}

// attention coeff in ORIGINAL edge order, then single 8B scattered write
__global__ void k_fillatt(const int* __restrict__ ei, const float* __restrict__ ea,
                          const float* __restrict__ cvec, const float* __restrict__ dvec,
                          const float* __restrict__ Wa, const float* __restrict__ ba,
                          int* __restrict__ cur, float2* __restrict__ sa) {
  int e = blockIdx.x * blockDim.x + threadIdx.x;
  if (e >= EDGES) return;
  int s = ei[e], d = ei[EDGES + e];
  float alin = cvec[d] + dvec[s] + ea[3 * e] * Wa[128] + ea[3 * e + 1] * Wa[129] +
               ea[3 * e + 2] * Wa[130] + ba[0];
  float lr = alin >= 0.f ? alin : 0.01f * alin;
  float a = 1.f / (1.f + expf(-lr));
  int p = atomicAdd(&cur[d], 1);
  sa[p] = make_float2(__int_as_float(s), a);
}

// ---------------- fp16 helpers ----------------

__device__ __forceinline__ void store16h(__half* dst, const float* v) {
  uint u[8];
#pragma unroll
  for (int j = 0; j < 8; j++) {
    __half2 h = __float22half2_rn(make_float2(v[2 * j], v[2 * j + 1]));
    u[j] = *reinterpret_cast<uint*>(&h);
  }
  uint4* o = (uint4*)dst;
  o[0] = make_uint4(u[0], u[1], u[2], u[3]);
  o[1] = make_uint4(u[4], u[5], u[6], u[7]);
}

__device__ __forceinline__ void store8h(__half* dst, const float* v) {
  uint u[4];
#pragma unroll
  for (int j = 0; j < 4; j++) {
    __half2 h = __float22half2_rn(make_float2(v[2 * j], v[2 * j + 1]));
    u[j] = *reinterpret_cast<uint*>(&h);
  }
  *(uint4*)dst = make_uint4(u[0], u[1], u[2], u[3]);
}

__device__ __forceinline__ float4 h4tof4(uint2 u) {
  float2 fa = __half22float2(*reinterpret_cast<__half2*>(&u.x));
  float2 fb = __half22float2(*reinterpret_cast<__half2*>(&u.y));
  return make_float4(fa.x, fa.y, fb.x, fb.y);
}

// dual-node gather with EXPLICIT load batching: all 8 sa loads, then all 8 row
// loads, then all converts/FMAs -> 8 row-gathers genuinely in flight per wave.
__device__ __forceinline__ void gather_pair(
    const __half* __restrict__ tab, const float2* __restrict__ sa,
    int sA, int eA, int sB, int eB, int sub, int col,
    float4& outA, float4& outB) {
  int lenA = eA - sA, lenB = eB - sB;
  int lastA = (lenA > 0) ? eA - 1 : 0;
  int lastB = (lenB > 0) ? eB - 1 : 0;
  float4 accA = make_float4(0.f, 0.f, 0.f, 0.f);
  float4 accB = make_float4(0.f, 0.f, 0.f, 0.f);
  int iters = (max(lenA, lenB) + 15) >> 4;
  int mA = sA, mB = sB;
  for (int it = 0; it < iters; ++it, mA += 16, mB += 16) {
    float2 sv[8];
#pragma unroll
    for (int q = 0; q < 4; q++) sv[q] = sa[min(mA + sub + 4 * q, lastA)];
#pragma unroll
    for (int q = 0; q < 4; q++) sv[4 + q] = sa[min(mB + sub + 4 * q, lastB)];
    uint2 u[8];
#pragma unroll
    for (int q = 0; q < 8; q++)
      u[q] = *((const uint2*)(tab + (size_t)__float_as_int(sv[q].x) * HD) + col);
#pragma unroll
    for (int q = 0; q < 4; q++) {
      float w = (mA + sub + 4 * q < eA) ? 1.f : 0.f;
      float4 f = h4tof4(u[q]);
      accA.x = fmaf(w, f.x, accA.x); accA.y = fmaf(w, f.y, accA.y);
      accA.z = fmaf(w, f.z, accA.z); accA.w = fmaf(w, f.w, accA.w);
    }
#pragma unroll
    for (int q = 0; q < 4; q++) {
      float w = (mB + sub + 4 * q < eB) ? 1.f : 0.f;
      float4 f = h4tof4(u[4 + q]);
      accB.x = fmaf(w, f.x, accB.x); accB.y = fmaf(w, f.y, accB.y);
      accB.z = fmaf(w, f.z, accB.z); accB.w = fmaf(w, f.w, accB.w);
    }
  }
#pragma unroll
  for (int off = 16; off <= 32; off <<= 1) {
    accA.x += __shfl_xor(accA.x, off); accA.y += __shfl_xor(accA.y, off);
    accA.z += __shfl_xor(accA.z, off); accA.w += __shfl_xor(accA.w, off);
    accB.x += __shfl_xor(accB.x, off); accB.y += __shfl_xor(accB.y, off);
    accB.z += __shfl_xor(accB.z, off); accB.w += __shfl_xor(accB.w, off);
  }
  outA = accA; outB = accB;
}

// single-node weighted gather for the standalone attention aggregation
__device__ __forceinline__ float4 gather_att(
    const __half* __restrict__ tab, const float2* __restrict__ sa,
    int start, int end, int sub, int col) {
  int len = end - start;
  int last = (len > 0) ? end - 1 : 0;
  float4 a0 = make_float4(0.f, 0.f, 0.f, 0.f), a1 = a0, a2 = a0, a3 = a0;
  for (int m = start; m < end; m += 16) {
    float2 sv[4];
#pragma unroll
    for (int q = 0; q < 4; q++) sv[q] = sa[min(m + sub + 4 * q, last)];
    uint2 u[4];
#pragma unroll
    for (int q = 0; q < 4; q++)
      u[q] = *((const uint2*)(tab + (size_t)__float_as_int(sv[q].x) * HD) + col);
    float w[4];
#pragma unroll
    for (int q = 0; q < 4; q++) w[q] = (m + sub + 4 * q < end) ? sv[q].y : 0.f;
    float4 f0 = h4tof4(u[0]), f1 = h4tof4(u[1]), f2 = h4tof4(u[2]), f3 = h4tof4(u[3]);
    a0.x = fmaf(w[0], f0.x, a0.x); a0.y = fmaf(w[0], f0.y, a0.y);
    a0.z = fmaf(w[0], f0.z, a0.z); a0.w = fmaf(w[0], f0.w, a0.w);
    a1.x = fmaf(w[1], f1.x, a1.x); a1.y = fmaf(w[1], f1.y, a1.y);
    a1.z = fmaf(w[1], f1.z, a1.z); a1.w = fmaf(w[1], f1.w, a1.w);
    a2.x = fmaf(w[2], f2.x, a2.x); a2.y = fmaf(w[2], f2.y, a2.y);
    a2.z = fmaf(w[2], f2.z, a2.z); a2.w = fmaf(w[2], f2.w, a2.w);
    a3.x = fmaf(w[3], f3.x, a3.x); a3.y = fmaf(w[3], f3.y, a3.y);
    a3.z = fmaf(w[3], f3.z, a3.z); a3.w = fmaf(w[3], f3.w, a3.w);
  }
  float4 r;
  r.x = (a0.x + a1.x) + (a2.x + a3.x);
  r.y = (a0.y + a1.y) + (a2.y + a3.y);
  r.z = (a0.z + a1.z) + (a2.z + a3.z);
  r.w = (a0.w + a1.w) + (a2.w + a3.w);
#pragma unroll
  for (int off = 16; off <= 32; off <<= 1) {
    r.x += __shfl_xor(r.x, off); r.y += __shfl_xor(r.y, off);
    r.z += __shfl_xor(r.z, off); r.w += __shfl_xor(r.w, off);
  }
  return r;
}

// ---------------- kernels ----------------

// lin0: h = x@Wn + bn -> hA, LDS ; h0 = h@Wl + bl -> hB16 ; cvec/dvec dots
__global__ __launch_bounds__(256) void k_lin0(
    const float* __restrict__ x,
    const float* __restrict__ Wn, const float* __restrict__ bn,
    const float* __restrict__ Wl, const float* __restrict__ bl,
    const float* __restrict__ Wa,
    float* __restrict__ hA, __half* __restrict__ hB16,
    float* __restrict__ cvec, float* __restrict__ dvec) {
  __shared__ float sh[64 * LP];
  __shared__ float sc[4][64], sd[4][64];
  int slot = threadIdx.x & 63;
  int cc = __builtin_amdgcn_readfirstlane(threadIdx.x >> 6);
  int c0 = cc * 16;
  int n0 = blockIdx.x * 64 + slot;
  bool valid = n0 < NODES;
  int n = valid ? n0 : NODES - 1;
  const float4* xr = (const float4*)(x + (size_t)n * NFD);
  float acc[16];
#pragma unroll
  for (int j = 0; j < 16; j++) acc[j] = bn[c0 + j];
#pragma unroll
  for (int q = 0; q < 4; q++) {
    float4 xa = xr[q];
    float xs[4] = {xa.x, xa.y, xa.z, xa.w};
#pragma unroll
    for (int t = 0; t < 4; t++)
#pragma unroll
      for (int j = 0; j < 16; j++)
        acc[j] = fmaf(xs[t], Wn[(q * 4 + t) * HD + c0 + j], acc[j]);
  }
#pragma unroll
  for (int j = 0; j < 16; j++) sh[slot * LP + c0 + j] = acc[j];
  if (valid) {
    float4* o = (float4*)(hA + (size_t)n * HD + c0);
    o[0] = make_float4(acc[0], acc[1], acc[2], acc[3]);
    o[1] = make_float4(acc[4], acc[5], acc[6], acc[7]);
    o[2] = make_float4(acc[8], acc[9], acc[10], acc[11]);
    o[3] = make_float4(acc[12], acc[13], acc[14], acc[15]);
  }
  __syncthreads();
  float a2[16];
#pragma unroll
  for (int j = 0; j < 16; j++) a2[j] = bl[c0 + j];
#pragma unroll 8
  for (int k = 0; k < 64; k++) {
    float hk = sh[slot * LP + k];
#pragma unroll
    for (int j = 0; j < 16; j++)
      a2[j] = fmaf(hk, Wl[k * HD + c0 + j], a2[j]);
  }
  float cn = 0.f, dn = 0.f;
#pragma unroll
  for (int j = 0; j < 16; j++) {
    cn = fmaf(a2[j], Wa[c0 + j], cn);
    dn = fmaf(a2[j], Wa[64 + c0 + j], dn);
  }
  if (valid) store16h(hB16 + (size_t)n * HD + c0, a2);
  sc[cc][slot] = cn;
  sd[cc][slot] = dn;
  __syncthreads();
  if (cc == 0 && valid) {
    cvec[n] = sc[0][slot] + sc[1][slot] + sc[2][slot] + sc[3][slot];
    dvec[n] = sd[0][slot] + sd[1][slot] + sd[2][slot] + sd[3][slot];
  }
}

// layer0 aggregation: gather hB16, write hC (fp32) + hC16
__global__ __launch_bounds__(256) void k_agg_att(
    const float2* __restrict__ sa, const int* __restrict__ rowptr,
    const float* __restrict__ hA, const __half* __restrict__ hB16,
    const float* __restrict__ g, const float* __restrict__ bt,
    float* __restrict__ hC, __half* __restrict__ hC16) {
  int lane = threadIdx.x & 63;
  int node = __builtin_amdgcn_readfirstlane(blockIdx.x * 4 + (threadIdx.x >> 6));
  if (node >= NODES) return;
  int start = rowptr[node], end = rowptr[node + 1];
  int sub = lane >> 4, col = lane & 15;
  float4 gg = ((const float4*)g)[col];
  float4 bb = ((const float4*)bt)[col];
  float4 ha = *((const float4*)(hA + (size_t)node * HD) + col);
  float4 accr = gather_att(hB16, sa, start, end, sub, col);
  if (lane < 16) {
    float4 v;
    v.x = fmaxf(accr.x * (gg.x * BN_INV) + bb.x, 0.f) + ha.x;
    v.y = fmaxf(accr.y * (gg.y * BN_INV) + bb.y, 0.f) + ha.y;
    v.z = fmaxf(accr.z * (gg.z * BN_INV) + bb.z, 0.f) + ha.z;
    v.w = fmaxf(accr.w * (gg.w * BN_INV) + bb.w, 0.f) + ha.w;
    *((float4*)(hC + (size_t)node * HD) + col) = v;
    __half2 p0 = __float22half2_rn(make_float2(v.x, v.y));
    __half2 p1 = __float22half2_rn(make_float2(v.z, v.w));
    uint2 u;
    u.x = *reinterpret_cast<uint*>(&p0);
    u.y = *reinterpret_cast<uint*>(&p1);
    *((uint2*)(hC16 + (size_t)node * HD) + col) = u;
  }
}

// FUSED mean-gather (hC16) + SAGE + GCN pre-GEMM. 512 threads: 8 waves.
__global__ __launch_bounds__(512) void k_msage(
    const float2* __restrict__ sa, const int* __restrict__ rowptr,
    const float* __restrict__ hC, const __half* __restrict__ hC16,
    const float* __restrict__ Wl, const float* __restrict__ bl,
    const float* __restrict__ Wr, const float* __restrict__ Wg,
    const float* __restrict__ g, const float* __restrict__ bt,
    const float* __restrict__ dis,
    float* __restrict__ hA, __half* __restrict__ hD16) {
  __shared__ float sh[64 * LP];
  int lane = threadIdx.x & 63;
  int wu = __builtin_amdgcn_readfirstlane(threadIdx.x >> 6);  // 0..7
  int sub = lane >> 4, col = lane & 15;
  int nbase = blockIdx.x * 64;
  // phase 1: mean-gather, 2 nodes per wave-step, 8 loads in flight
  for (int i = 0; i < 8; i += 2) {
    int slotA = wu * 8 + i, slotB = slotA + 1;
    int nA = min(nbase + slotA, NODES - 1);
    int nB = min(nbase + slotB, NODES - 1);
    int sA = rowptr[nA], eA = rowptr[nA + 1];
    int sB = rowptr[nB], eB = rowptr[nB + 1];
    float rdA = 1.f / fmaxf((float)(eA - sA), 1.f);
    float rdB = 1.f / fmaxf((float)(eB - sB), 1.f);
    float4 ra, rb;
    gather_pair(hC16, sa, sA, eA, sB, eB, sub, col, ra, rb);
    if (lane < 16) {
      sh[slotA * LP + col * 4 + 0] = ra.x * rdA;
      sh[slotA * LP + col * 4 + 1] = ra.y * rdA;
      sh[slotA * LP + col * 4 + 2] = ra.z * rdA;
      sh[slotA * LP + col * 4 + 3] = ra.w * rdA;
      sh[slotB * LP + col * 4 + 0] = rb.x * rdB;
      sh[slotB * LP + col * 4 + 1] = rb.y * rdB;
      sh[slotB * LP + col * 4 + 2] = rb.z * rdB;
      sh[slotB * LP + col * 4 + 3] = rb.w * rdB;
    }
  }
  __syncthreads();
  // phase 2: GEMMs, 8 cols per wave
  int c0 = wu * 8;
  int n0 = nbase + lane;
  bool valid = n0 < NODES;
  int n = valid ? n0 : NODES - 1;
  const float4* cr = (const float4*)(hC + (size_t)n * HD);
  float acc[8];
#pragma unroll
  for (int j = 0; j < 8; j++) acc[j] = bl[c0 + j];
#pragma unroll 8
  for (int k = 0; k < 64; k++) {
    float mk = sh[lane * LP + k];
#pragma unroll
    for (int j = 0; j < 8; j++)
      acc[j] = fmaf(mk, Wl[k * HD + c0 + j], acc[j]);
  }
#pragma unroll 4
  for (int q = 0; q < 16; q++) {
    float4 ac = cr[q];
    float cs[4] = {ac.x, ac.y, ac.z, ac.w};
#pragma unroll
    for (int t = 0; t < 4; t++)
#pragma unroll
      for (int j = 0; j < 8; j++)
        acc[j] = fmaf(cs[t], Wr[(q * 4 + t) * HD + c0 + j], acc[j]);
  }
  float tv[8];
  {
    float4 r0 = cr[wu * 2], r1 = cr[wu * 2 + 1];
    float rv[8] = {r0.x, r0.y, r0.z, r0.w, r1.x, r1.y, r1.z, r1.w};
#pragma unroll
    for (int j = 0; j < 8; j++)
      tv[j] = fmaxf(acc[j] * (g[c0 + j] * BN_INV) + bt[c0 + j], 0.f) + rv[j];
  }
  __syncthreads();  // mean rows fully consumed -> safe to overwrite
#pragma unroll
  for (int j = 0; j < 8; j++) sh[lane * LP + c0 + j] = tv[j];
  if (valid) {
    float4* o = (float4*)(hA + (size_t)n * HD + c0);
    o[0] = make_float4(tv[0], tv[1], tv[2], tv[3]);
    o[1] = make_float4(tv[4], tv[5], tv[6], tv[7]);
  }
  __syncthreads();
  float di = dis[n];
  float a2[8];
#pragma unroll
  for (int j = 0; j < 8; j++) a2[j] = 0.f;
#pragma unroll 8
  for (int k = 0; k < 64; k++) {
    float tk = sh[lane * LP + k];
#pragma unroll
    for (int j = 0; j < 8; j++)
      a2[j] = fmaf(tk, Wg[k * HD + c0 + j], a2[j]);
  }
#pragma unroll
  for (int j = 0; j < 8; j++) a2[j] *= di;
  if (valid) store8h(hD16 + (size_t)n * HD + c0, a2);
}

// FUSED GCN aggregation (gather hD16) + regressor head -> out. 512 threads.
__global__ __launch_bounds__(512) void k_gcnreg(
    const float2* __restrict__ sa, const int* __restrict__ rowptr,
    const float* __restrict__ dis,
    const float* __restrict__ hA,     // t (residual ident)
    const __half* __restrict__ hD16,  // fp16 gather/self table
    const float* __restrict__ bg,
    const float* __restrict__ g, const float* __restrict__ bt,
    const float* __restrict__ W1, const float* __restrict__ b1,
    const float* __restrict__ W2, const float* __restrict__ b2,
    const float* __restrict__ W3, const float* __restrict__ b3,
    float* __restrict__ out) {
  __shared__ float sh[64 * LP];
  __shared__ float sred[8][64];
  int lane = threadIdx.x & 63;
  int wu = __builtin_amdgcn_readfirstlane(threadIdx.x >> 6);  // 0..7
  int sub = lane >> 4, col = lane & 15;
  int nbase = blockIdx.x * 64;
  float4 gg = ((const float4*)g)[col];
  float4 bb = ((const float4*)bt)[col];
  float4 bgv = ((const float4*)bg)[col];
  // phase 1: gcn-gather + epilogue, 2 nodes per wave-step
  for (int i = 0; i < 8; i += 2) {
    int slotA = wu * 8 + i, slotB = slotA + 1;
    int nA = min(nbase + slotA, NODES - 1);
    int nB = min(nbase + slotB, NODES - 1);
    int sA = rowptr[nA], eA = rowptr[nA + 1];
    int sB = rowptr[nB], eB = rowptr[nB + 1];
    float diA = dis[nA], diB = dis[nB];
    float4 svA = h4tof4(*((const uint2*)(hD16 + (size_t)nA * HD) + col));
    float4 svB = h4tof4(*((const uint2*)(hD16 + (size_t)nB * HD) + col));
    float4 haA = *((const float4*)(hA + (size_t)nA * HD) + col);
    float4 haB = *((const float4*)(hA + (size_t)nB * HD) + col);
    float4 ra, rb;
    gather_pair(hD16, sa, sA, eA, sB, eB, sub, col, ra, rb);
    if (lane < 16) {
      sh[slotA * LP + col * 4 + 0] =
          fmaxf((diA * (ra.x + svA.x) + bgv.x) * (gg.x * BN_INV) + bb.x, 0.f) + haA.x;
      sh[slotA * LP + col * 4 + 1] =
          fmaxf((diA * (ra.y + svA.y) + bgv.y) * (gg.y * BN_INV) + bb.y, 0.f) + haA.y;
      sh[slotA * LP + col * 4 + 2] =
          fmaxf((diA * (ra.z + svA.z) + bgv.z) * (gg.z * BN_INV) + bb.z, 0.f) + haA.z;
      sh[slotA * LP + col * 4 + 3] =
          fmaxf((diA * (ra.w + svA.w) + bgv.w) * (gg.w * BN_INV) + bb.w, 0.f) + haA.w;
      sh[slotB * LP + col * 4 + 0] =
          fmaxf((diB * (rb.x + svB.x) + bgv.x) * (gg.x * BN_INV) + bb.x, 0.f) + haB.x;
      sh[slotB * LP + col * 4 + 1] =
          fmaxf((diB * (rb.y + svB.y) + bgv.y) * (gg.y * BN_INV) + bb.y, 0.f) + haB.y;
      sh[slotB * LP + col * 4 + 2] =
          fmaxf((diB * (rb.z + svB.z) + bgv.z) * (gg.z * BN_INV) + bb.z, 0.f) + haB.z;
      sh[slotB * LP + col * 4 + 3] =
          fmaxf((diB * (rb.w + svB.w) + bgv.w) * (gg.w * BN_INV) + bb.w, 0.f) + haB.w;
    }
  }
  __syncthreads();
  // phase 2: regressor GEMM chain from LDS, 8 cols per wave
  int c0 = wu * 8;
  int n0 = nbase + lane;
  bool valid = n0 < NODES;
  int n = valid ? n0 : NODES - 1;
  float acc[8];
#pragma unroll
  for (int j = 0; j < 8; j++) acc[j] = b1[c0 + j];
#pragma unroll 8
  for (int k = 0; k < 64; k++) {
    float rk = sh[lane * LP + k];
#pragma unroll
    for (int j = 0; j < 8; j++)
      acc[j] = fmaf(rk, W1[k * HD + c0 + j], acc[j]);
  }
  float t1v[8];
#pragma unroll
  for (int j = 0; j < 8; j++) t1v[j] = fmaxf(acc[j], 0.f);
  __syncthreads();  // layer2 rows consumed -> overwrite with t1
#pragma unroll
  for (int j = 0; j < 8; j++) sh[lane * LP + c0 + j] = t1v[j];
  __syncthreads();
  int d0 = wu * 4;
  float a2[4];
#pragma unroll
  for (int j = 0; j < 4; j++) a2[j] = b2[d0 + j];
#pragma unroll 8
  for (int k = 0; k < 64; k++) {
    float tk = sh[lane * LP + k];
#pragma unroll
    for (int j = 0; j < 4; j++)
      a2[j] = fmaf(tk, W2[k * 32 + d0 + j], a2[j]);
  }
  float part = 0.f;
#pragma unroll
  for (int j = 0; j < 4; j++) part = fmaf(fmaxf(a2[j], 0.f), W3[d0 + j], part);
  sred[wu][lane] = part;
  __syncthreads();
  if (wu == 0 && valid) {
    float s = b3[0];
#pragma unroll
    for (int w = 0; w < 8; w++) s += sred[w][lane];
    out[n] = s;
  }
}

// ---------------- host launch ----------------

extern "C" void kernel_launch(void* const* d_in, const int* in_sizes, int n_in,
                              void* d_out, int out_size, void* d_ws, size_t ws_size,
                              hipStream_t stream) {
  const float* x      = (const float*)d_in[0];
  const float* ea     = (const float*)d_in[1];
  const int*   ei     = (const int*)d_in[2];
  const float* W_node = (const float*)d_in[3];
  const float* b_node = (const float*)d_in[4];
  // d_in[5], d_in[6]: W_edge/b_edge — unused by the reference output
  const float* W_lin0 = (const float*)d_in[7];
  const float* b_lin0 = (const float*)d_in[8];
  const float* W_att0 = (const float*)d_in[9];
  const float* b_att0 = (const float*)d_in[10];
  const float* W_sl   = (const float*)d_in[11];
  const float* b_sl   = (const float*)d_in[12];
  const float* W_sr   = (const float*)d_in[13];
  const float* W_gcn  = (const float*)d_in[14];
  const float* b_gcn  = (const float*)d_in[15];
  const float* bn_g   = (const float*)d_in[16];  // [3,64]
  const float* bn_b   = (const float*)d_in[17];
  const float* W_r1   = (const float*)d_in[18];
  const float* b_r1   = (const float*)d_in[19];
  const float* W_r2   = (const float*)d_in[20];
  const float* b_r2   = (const float*)d_in[21];
  const float* W_r3   = (const float*)d_in[22];
  const float* b_r3   = (const float*)d_in[23];
  float* out = (float*)d_out;

  char* ws = (char*)d_ws;
  size_t o = 0;
  auto alloc = [&](size_t bytes) -> void* {
    void* p = ws + o;
    o += (bytes + 255) & ~(size_t)255;
    return p;
  };
  int*    deg    = (int*)alloc(NODES * 4);
  int*    rowptr = (int*)alloc((NODES + 1) * 4);
  int*    cur    = (int*)alloc(NODES * 4);
  int*    part   = (int*)alloc(256 * 4);
  float2* sa     = (float2*)alloc((size_t)EDGES * 8);
  float*  hA     = (float*)alloc((size_t)NODES * HD * 4);
  float*  hC     = (float*)alloc((size_t)NODES * HD * 4);
  __half* hB16   = (__half*)alloc((size_t)NODES * HD * 2);
  __half* hC16   = (__half*)alloc((size_t)NODES * HD * 2);
  __half* hD16   = (__half*)alloc((size_t)NODES * HD * 2);
  float*  cvec   = (float*)alloc(NODES * 4);
  float*  dvec   = (float*)alloc(NODES * 4);
  float*  dis    = (float*)alloc(NODES * 4);
  (void)ws_size; (void)in_sizes; (void)n_in; (void)out_size;

  const int EB  = (EDGES + 255) / 256;
  const int NT  = (NODES + 63) / 64;     // 64 nodes/block
  const int NBW = (NODES + 3) / 4;       // wave-per-node (4 waves/block)

  hipMemsetAsync(deg, 0, NODES * 4, stream);
  k_hist<<<EB, 256, 0, stream>>>(ei, deg);
  k_scan1<<<NCHUNK, 256, 0, stream>>>(deg, part);
  k_scan2<<<1, 64, 0, stream>>>(part);
  k_scan3<<<NCHUNK, 256, 0, stream>>>(deg, part, rowptr, cur, dis);

  k_lin0<<<NT, 256, 0, stream>>>(x, W_node, b_node, W_lin0, b_lin0, W_att0,
                                 hA, hB16, cvec, dvec);
  k_fillatt<<<EB, 256, 0, stream>>>(ei, ea, cvec, dvec, W_att0, b_att0, cur, sa);
  k_agg_att<<<NBW, 256, 0, stream>>>(sa, rowptr, hA, hB16,
                                     bn_g + 0 * HD, bn_b + 0 * HD, hC, hC16);
  // fused mean-gather + SAGE + GCN pre-GEMM: t -> hA, hBp -> hD16 only
  k_msage<<<NT, 512, 0, stream>>>(sa, rowptr, hC, hC16, W_sl, b_sl, W_sr, W_gcn,
                                  bn_g + 1 * HD, bn_b + 1 * HD, dis, hA, hD16);
  // fused GCN aggregation + regressor -> out
  k_gcnreg<<<NT, 512, 0, stream>>>(sa, rowptr, dis, hA, hD16, b_gcn,
                                   bn_g + 2 * HD, bn_b + 2 * HD,
                                   W_r1, b_r1, W_r2, b_r2, W_r3, b_r3, out);
}

// Round 13
// 312.734 us; speedup vs baseline: 1.1935x; 1.1935x over previous
//
#include <hip/hip_runtime.h>
#include <hip/hip_fp16.h>
#include <math.h>

#define NODES 100000
#define EDGES 1250000
#define HD 64
#define NFD 16
#define CHUNK 1024
#define NCHUNK ((NODES + CHUNK - 1) / CHUNK)
#define BN_INV 0.9999950000374996f  // 1/sqrt(1+1e-5)
#define LP 65  // LDS row pitch: 65 % 32 == 1 -> 2-way bank aliasing (free)
#define SRCMASK 0x1FFFFu
#define WSCALE (1.0f / 32768.0f)

// ---------------- graph build ----------------

__global__ void k_hist(const int* __restrict__ ei, int* __restrict__ deg) {
  int e = blockIdx.x * blockDim.x + threadIdx.x;
  if (e < EDGES) atomicAdd(&deg[ei[EDGES + e]], 1);
}

__global__ void k_scan1(const int* __restrict__ deg, int* __restrict__ part) {
  __shared__ int lds[256];
  int t = threadIdx.x, b = blockIdx.x;
  int base = b * CHUNK + t * 4;
  int s = 0;
#pragma unroll
  for (int m = 0; m < 4; m++) { int i = base + m; if (i < NODES) s += deg[i]; }
  lds[t] = s; __syncthreads();
  for (int off = 128; off > 0; off >>= 1) {
    if (t < off) lds[t] += lds[t + off];
    __syncthreads();
  }
  if (t == 0) part[b] = lds[0];
}

__global__ void k_scan2(int* __restrict__ part) {
  if (threadIdx.x == 0 && blockIdx.x == 0) {
    int run = 0;
    for (int c = 0; c < NCHUNK; c++) { int v = part[c]; part[c] = run; run += v; }
  }
}

__global__ void k_scan3(const int* __restrict__ deg, const int* __restrict__ part,
                        int* __restrict__ rowptr, int* __restrict__ cur,
                        float* __restrict__ dis) {
  __shared__ int lds[256];
  int t = threadIdx.x, b = blockIdx.x;
  int base = b * CHUNK + t * 4;
  int dl[4]; int s = 0;
#pragma unroll
  for (int m = 0; m < 4; m++) { int i = base + m; dl[m] = (i < NODES) ? deg[i] : 0; s += dl[m]; }
  lds[t] = s; __syncthreads();
  for (int off = 1; off < 256; off <<= 1) {
    int add = (t >= off) ? lds[t - off] : 0;
    __syncthreads();
    lds[t] += add;
    __syncthreads();
  }
  int run = part[b] + lds[t] - s;  // exclusive prefix for this thread
#pragma unroll
  for (int m = 0; m < 4; m++) {
    int i = base + m;
    if (i < NODES) {
      rowptr[i] = run; cur[i] = run;
      dis[i] = 1.0f / sqrtf((float)(dl[m] + 1));  // GCN: indeg + self-loop
    }
    run += dl[m];
  }
  if (b == 0 && t == 0) rowptr[NODES] = EDGES;
}

// attention coeff in ORIGINAL edge order; packed 4B scatter: (q15(a)<<17)|src
__global__ void k_fillatt(const int* __restrict__ ei, const float* __restrict__ ea,
                          const float* __restrict__ cvec, const float* __restrict__ dvec,
                          const float* __restrict__ Wa, const float* __restrict__ ba,
                          int* __restrict__ cur, uint* __restrict__ sa) {
  int e = blockIdx.x * blockDim.x + threadIdx.x;
  if (e >= EDGES) return;
  int s = ei[e], d = ei[EDGES + e];
  float alin = cvec[d] + dvec[s] + ea[3 * e] * Wa[128] + ea[3 * e + 1] * Wa[129] +
               ea[3 * e + 2] * Wa[130] + ba[0];
  float lr = alin >= 0.f ? alin : 0.01f * alin;
  float a = 1.f / (1.f + expf(-lr));
  uint q = min((int)(a * 32768.f + 0.5f), 32767);
  int p = atomicAdd(&cur[d], 1);
  sa[p] = (q << 17) | (uint)s;
}

// ---------------- fp16 helpers ----------------

__device__ __forceinline__ void store16h(__half* dst, const float* v) {
  uint u[8];
#pragma unroll
  for (int j = 0; j < 8; j++) {
    __half2 h = __float22half2_rn(make_float2(v[2 * j], v[2 * j + 1]));
    u[j] = *reinterpret_cast<uint*>(&h);
  }
  uint4* o = (uint4*)dst;
  o[0] = make_uint4(u[0], u[1], u[2], u[3]);
  o[1] = make_uint4(u[4], u[5], u[6], u[7]);
}

__device__ __forceinline__ float4 h4tof4(uint2 u) {
  float2 fa = __half22float2(*reinterpret_cast<__half2*>(&u.x));
  float2 fb = __half22float2(*reinterpret_cast<__half2*>(&u.y));
  return make_float4(fa.x, fa.y, fb.x, fb.y);
}

// one 16-edge gather step (4 edge slots x 16 col-lanes), fp16 rows, packed sa
__device__ __forceinline__ void gstep(const __half* __restrict__ tab,
                                      const uint* __restrict__ sa,
                                      int m, int end, int last, int sub, int col,
                                      bool weighted,
                                      float4& A0, float4& A1, float4& A2, float4& A3) {
  int e0 = m + sub, e1 = e0 + 4, e2 = e0 + 8, e3 = e0 + 12;
  uint s0 = sa[min(e0, last)], s1 = sa[min(e1, last)];
  uint s2 = sa[min(e2, last)], s3 = sa[min(e3, last)];
  float w0 = (e0 < end) ? (weighted ? (float)(s0 >> 17) * WSCALE : 1.f) : 0.f;
  float w1 = (e1 < end) ? (weighted ? (float)(s1 >> 17) * WSCALE : 1.f) : 0.f;
  float w2 = (e2 < end) ? (weighted ? (float)(s2 >> 17) * WSCALE : 1.f) : 0.f;
  float w3 = (e3 < end) ? (weighted ? (float)(s3 >> 17) * WSCALE : 1.f) : 0.f;
  uint2 u0 = *((const uint2*)(tab + (size_t)(s0 & SRCMASK) * HD) + col);
  uint2 u1 = *((const uint2*)(tab + (size_t)(s1 & SRCMASK) * HD) + col);
  uint2 u2 = *((const uint2*)(tab + (size_t)(s2 & SRCMASK) * HD) + col);
  uint2 u3 = *((const uint2*)(tab + (size_t)(s3 & SRCMASK) * HD) + col);
  {
    float4 f = h4tof4(u0);
    A0.x = fmaf(w0, f.x, A0.x); A0.y = fmaf(w0, f.y, A0.y);
    A0.z = fmaf(w0, f.z, A0.z); A0.w = fmaf(w0, f.w, A0.w);
  }
  {
    float4 f = h4tof4(u1);
    A1.x = fmaf(w1, f.x, A1.x); A1.y = fmaf(w1, f.y, A1.y);
    A1.z = fmaf(w1, f.z, A1.z); A1.w = fmaf(w1, f.w, A1.w);
  }
  {
    float4 f = h4tof4(u2);
    A2.x = fmaf(w2, f.x, A2.x); A2.y = fmaf(w2, f.y, A2.y);
    A2.z = fmaf(w2, f.z, A2.z); A2.w = fmaf(w2, f.w, A2.w);
  }
  {
    float4 f = h4tof4(u3);
    A3.x = fmaf(w3, f.x, A3.x); A3.y = fmaf(w3, f.y, A3.y);
    A3.z = fmaf(w3, f.z, A3.z); A3.w = fmaf(w3, f.w, A3.w);
  }
}

__device__ __forceinline__ float4 red4(float4 a0, float4 a1, float4 a2, float4 a3) {
  float4 r;
  r.x = (a0.x + a1.x) + (a2.x + a3.x);
  r.y = (a0.y + a1.y) + (a2.y + a3.y);
  r.z = (a0.z + a1.z) + (a2.z + a3.z);
  r.w = (a0.w + a1.w) + (a2.w + a3.w);
#pragma unroll
  for (int off = 16; off <= 32; off <<= 1) {
    r.x += __shfl_xor(r.x, off); r.y += __shfl_xor(r.y, off);
    r.z += __shfl_xor(r.z, off); r.w += __shfl_xor(r.w, off);
  }
  return r;
}

#define AGG_BODY16(TABLE, WEIGHTED)                                              \
  float4 acc0 = make_float4(0.f, 0.f, 0.f, 0.f);                                 \
  float4 acc1 = make_float4(0.f, 0.f, 0.f, 0.f);                                 \
  float4 acc2 = make_float4(0.f, 0.f, 0.f, 0.f);                                 \
  float4 acc3 = make_float4(0.f, 0.f, 0.f, 0.f);                                 \
  int last = end - 1;                                                            \
  for (int m = start; m < end; m += 16)                                          \
    gstep(TABLE, sa, m, end, last, sub, col, WEIGHTED, acc0, acc1, acc2, acc3);  \
  float4 accr = red4(acc0, acc1, acc2, acc3);

// ---------------- kernels ----------------

// lin0: h = x@Wn + bn -> hA, LDS ; h0 = h@Wl + bl -> hB16 ; cvec/dvec dots
__global__ __launch_bounds__(256) void k_lin0(
    const float* __restrict__ x,
    const float* __restrict__ Wn, const float* __restrict__ bn,
    const float* __restrict__ Wl, const float* __restrict__ bl,
    const float* __restrict__ Wa,
    float* __restrict__ hA, __half* __restrict__ hB16,
    float* __restrict__ cvec, float* __restrict__ dvec) {
  __shared__ float sh[64 * LP];
  __shared__ float sc[4][64], sd[4][64];
  int slot = threadIdx.x & 63;
  int cc = __builtin_amdgcn_readfirstlane(threadIdx.x >> 6);
  int c0 = cc * 16;
  int n0 = blockIdx.x * 64 + slot;
  bool valid = n0 < NODES;
  int n = valid ? n0 : NODES - 1;
  const float4* xr = (const float4*)(x + (size_t)n * NFD);
  float acc[16];
#pragma unroll
  for (int j = 0; j < 16; j++) acc[j] = bn[c0 + j];
#pragma unroll
  for (int q = 0; q < 4; q++) {
    float4 xa = xr[q];
    float xs[4] = {xa.x, xa.y, xa.z, xa.w};
#pragma unroll
    for (int t = 0; t < 4; t++)
#pragma unroll
      for (int j = 0; j < 16; j++)
        acc[j] = fmaf(xs[t], Wn[(q * 4 + t) * HD + c0 + j], acc[j]);
  }
#pragma unroll
  for (int j = 0; j < 16; j++) sh[slot * LP + c0 + j] = acc[j];
  if (valid) {
    float4* o = (float4*)(hA + (size_t)n * HD + c0);
    o[0] = make_float4(acc[0], acc[1], acc[2], acc[3]);
    o[1] = make_float4(acc[4], acc[5], acc[6], acc[7]);
    o[2] = make_float4(acc[8], acc[9], acc[10], acc[11]);
    o[3] = make_float4(acc[12], acc[13], acc[14], acc[15]);
  }
  __syncthreads();
  float a2[16];
#pragma unroll
  for (int j = 0; j < 16; j++) a2[j] = bl[c0 + j];
#pragma unroll 8
  for (int k = 0; k < 64; k++) {
    float hk = sh[slot * LP + k];
#pragma unroll
    for (int j = 0; j < 16; j++)
      a2[j] = fmaf(hk, Wl[k * HD + c0 + j], a2[j]);
  }
  float cn = 0.f, dn = 0.f;
#pragma unroll
  for (int j = 0; j < 16; j++) {
    cn = fmaf(a2[j], Wa[c0 + j], cn);
    dn = fmaf(a2[j], Wa[64 + c0 + j], dn);
  }
  if (valid) store16h(hB16 + (size_t)n * HD + c0, a2);
  sc[cc][slot] = cn;
  sd[cc][slot] = dn;
  __syncthreads();
  if (cc == 0 && valid) {
    cvec[n] = sc[0][slot] + sc[1][slot] + sc[2][slot] + sc[3][slot];
    dvec[n] = sd[0][slot] + sd[1][slot] + sd[2][slot] + sd[3][slot];
  }
}

// layer0 aggregation: gather hB16 (weighted), write hC (fp32) + hC16
__global__ __launch_bounds__(256) void k_agg_att(
    const uint* __restrict__ sa, const int* __restrict__ rowptr,
    const float* __restrict__ hA, const __half* __restrict__ hB16,
    const float* __restrict__ g, const float* __restrict__ bt,
    float* __restrict__ hC, __half* __restrict__ hC16) {
  int lane = threadIdx.x & 63;
  int node = __builtin_amdgcn_readfirstlane(blockIdx.x * 4 + (threadIdx.x >> 6));
  if (node >= NODES) return;
  int start = rowptr[node], end = rowptr[node + 1];
  int sub = lane >> 4, col = lane & 15;
  float4 gg = ((const float4*)g)[col];
  float4 bb = ((const float4*)bt)[col];
  float4 ha = *((const float4*)(hA + (size_t)node * HD) + col);
  AGG_BODY16(hB16, true)
  if (lane < 16) {
    float4 v;
    v.x = fmaxf(accr.x * (gg.x * BN_INV) + bb.x, 0.f) + ha.x;
    v.y = fmaxf(accr.y * (gg.y * BN_INV) + bb.y, 0.f) + ha.y;
    v.z = fmaxf(accr.z * (gg.z * BN_INV) + bb.z, 0.f) + ha.z;
    v.w = fmaxf(accr.w * (gg.w * BN_INV) + bb.w, 0.f) + ha.w;
    *((float4*)(hC + (size_t)node * HD) + col) = v;
    __half2 p0 = __float22half2_rn(make_float2(v.x, v.y));
    __half2 p1 = __float22half2_rn(make_float2(v.z, v.w));
    uint2 u;
    u.x = *reinterpret_cast<uint*>(&p0);
    u.y = *reinterpret_cast<uint*>(&p1);
    *((uint2*)(hC16 + (size_t)node * HD) + col) = u;
  }
}

// FUSED mean-gather (hC16) + SAGE + GCN pre-GEMM. 256 threads (round-10 form).
__global__ __launch_bounds__(256) void k_msage(
    const uint* __restrict__ sa, const int* __restrict__ rowptr,
    const float* __restrict__ hC, const __half* __restrict__ hC16,
    const float* __restrict__ Wl, const float* __restrict__ bl,
    const float* __restrict__ Wr, const float* __restrict__ Wg,
    const float* __restrict__ g, const float* __restrict__ bt,
    const float* __restrict__ dis,
    float* __restrict__ hA, __half* __restrict__ hD16) {
  __shared__ float sh[64 * LP];
  int lane = threadIdx.x & 63;
  int wu = __builtin_amdgcn_readfirstlane(threadIdx.x >> 6);
  int sub = lane >> 4, col = lane & 15;
  int nbase = blockIdx.x * 64;
  // phase 1: mean-gather
  for (int i = 0; i < 16; i++) {
    int slot = wu * 16 + i;
    int nn = min(nbase + slot, NODES - 1);
    int start = rowptr[nn], end = rowptr[nn + 1];
    float rdeg = 1.f / fmaxf((float)(end - start), 1.f);
    AGG_BODY16(hC16, false)
    if (lane < 16) {
      sh[slot * LP + col * 4 + 0] = accr.x * rdeg;
      sh[slot * LP + col * 4 + 1] = accr.y * rdeg;
      sh[slot * LP + col * 4 + 2] = accr.z * rdeg;
      sh[slot * LP + col * 4 + 3] = accr.w * rdeg;
    }
  }
  __syncthreads();
  // phase 2: GEMMs, 16 cols per wave
  int c0 = wu * 16;
  int n0 = nbase + lane;
  bool valid = n0 < NODES;
  int n = valid ? n0 : NODES - 1;
  const float4* cr = (const float4*)(hC + (size_t)n * HD);
  float acc[16];
#pragma unroll
  for (int j = 0; j < 16; j++) acc[j] = bl[c0 + j];
#pragma unroll 8
  for (int k = 0; k < 64; k++) {
    float mk = sh[lane * LP + k];
#pragma unroll
    for (int j = 0; j < 16; j++)
      acc[j] = fmaf(mk, Wl[k * HD + c0 + j], acc[j]);
  }
#pragma unroll 4
  for (int q = 0; q < 16; q++) {
    float4 ac = cr[q];
    float cs[4] = {ac.x, ac.y, ac.z, ac.w};
#pragma unroll
    for (int t = 0; t < 4; t++)
#pragma unroll
      for (int j = 0; j < 16; j++)
        acc[j] = fmaf(cs[t], Wr[(q * 4 + t) * HD + c0 + j], acc[j]);
  }
  float tv[16];
  {
    float4 r0 = cr[wu * 4 + 0], r1 = cr[wu * 4 + 1], r2 = cr[wu * 4 + 2], r3 = cr[wu * 4 + 3];
    float rv[16] = {r0.x, r0.y, r0.z, r0.w, r1.x, r1.y, r1.z, r1.w,
                    r2.x, r2.y, r2.z, r2.w, r3.x, r3.y, r3.z, r3.w};
#pragma unroll
    for (int j = 0; j < 16; j++)
      tv[j] = fmaxf(acc[j] * (g[c0 + j] * BN_INV) + bt[c0 + j], 0.f) + rv[j];
  }
  __syncthreads();  // mean rows fully consumed -> safe to overwrite
#pragma unroll
  for (int j = 0; j < 16; j++) sh[lane * LP + c0 + j] = tv[j];
  if (valid) {
    float4* o = (float4*)(hA + (size_t)n * HD + c0);
    o[0] = make_float4(tv[0], tv[1], tv[2], tv[3]);
    o[1] = make_float4(tv[4], tv[5], tv[6], tv[7]);
    o[2] = make_float4(tv[8], tv[9], tv[10], tv[11]);
    o[3] = make_float4(tv[12], tv[13], tv[14], tv[15]);
  }
  __syncthreads();
  float di = dis[n];
  float a2[16];
#pragma unroll
  for (int j = 0; j < 16; j++) a2[j] = 0.f;
#pragma unroll 8
  for (int k = 0; k < 64; k++) {
    float tk = sh[lane * LP + k];
#pragma unroll
    for (int j = 0; j < 16; j++)
      a2[j] = fmaf(tk, Wg[k * HD + c0 + j], a2[j]);
  }
#pragma unroll
  for (int j = 0; j < 16; j++) a2[j] *= di;
  if (valid) store16h(hD16 + (size_t)n * HD + c0, a2);
}

// FUSED GCN aggregation (gather hD16) + regressor head -> out. 256 threads.
__global__ __launch_bounds__(256) void k_gcnreg(
    const uint* __restrict__ sa, const int* __restrict__ rowptr,
    const float* __restrict__ dis,
    const float* __restrict__ hA,     // t (residual ident)
    const __half* __restrict__ hD16,  // fp16 gather + self table
    const float* __restrict__ bg,
    const float* __restrict__ g, const float* __restrict__ bt,
    const float* __restrict__ W1, const float* __restrict__ b1,
    const float* __restrict__ W2, const float* __restrict__ b2,
    const float* __restrict__ W3, const float* __restrict__ b3,
    float* __restrict__ out) {
  __shared__ float sh[64 * LP];
  __shared__ float sred[4][64];
  int lane = threadIdx.x & 63;
  int wu = __builtin_amdgcn_readfirstlane(threadIdx.x >> 6);
  int sub = lane >> 4, col = lane & 15;
  int nbase = blockIdx.x * 64;
  float4 gg = ((const float4*)g)[col];
  float4 bb = ((const float4*)bt)[col];
  float4 bgv = ((const float4*)bg)[col];
  // phase 1: gcn-gather + epilogue -> layer2 output rows in LDS
  for (int i = 0; i < 16; i++) {
    int slot = wu * 16 + i;
    int nn = min(nbase + slot, NODES - 1);
    int start = rowptr[nn], end = rowptr[nn + 1];
    float di = dis[nn];
    float4 sv = h4tof4(*((const uint2*)(hD16 + (size_t)nn * HD) + col));  // self
    float4 ha = *((const float4*)(hA + (size_t)nn * HD) + col);
    AGG_BODY16(hD16, false)
    if (lane < 16) {
      sh[slot * LP + col * 4 + 0] =
          fmaxf((di * (accr.x + sv.x) + bgv.x) * (gg.x * BN_INV) + bb.x, 0.f) + ha.x;
      sh[slot * LP + col * 4 + 1] =
          fmaxf((di * (accr.y + sv.y) + bgv.y) * (gg.y * BN_INV) + bb.y, 0.f) + ha.y;
      sh[slot * LP + col * 4 + 2] =
          fmaxf((di * (accr.z + sv.z) + bgv.z) * (gg.z * BN_INV) + bb.z, 0.f) + ha.z;
      sh[slot * LP + col * 4 + 3] =
          fmaxf((di * (accr.w + sv.w) + bgv.w) * (gg.w * BN_INV) + bb.w, 0.f) + ha.w;
    }
  }
  __syncthreads();
  // phase 2: regressor GEMM chain from LDS
  int c0 = wu * 16;
  int n0 = nbase + lane;
  bool valid = n0 < NODES;
  int n = valid ? n0 : NODES - 1;
  float acc[16];
#pragma unroll
  for (int j = 0; j < 16; j++) acc[j] = b1[c0 + j];
#pragma unroll 8
  for (int k = 0; k < 64; k++) {
    float rk = sh[lane * LP + k];
#pragma unroll
    for (int j = 0; j < 16; j++)
      acc[j] = fmaf(rk, W1[k * HD + c0 + j], acc[j]);
  }
  float t1v[16];
#pragma unroll
  for (int j = 0; j < 16; j++) t1v[j] = fmaxf(acc[j], 0.f);
  __syncthreads();  // layer2 rows consumed -> overwrite with t1
#pragma unroll
  for (int j = 0; j < 16; j++) sh[lane * LP + c0 + j] = t1v[j];
  __syncthreads();
  int d0 = wu * 8;
  float a2[8];
#pragma unroll
  for (int j = 0; j < 8; j++) a2[j] = b2[d0 + j];
#pragma unroll 8
  for (int k = 0; k < 64; k++) {
    float tk = sh[lane * LP + k];
#pragma unroll
    for (int j = 0; j < 8; j++)
      a2[j] = fmaf(tk, W2[k * 32 + d0 + j], a2[j]);
  }
  float part = 0.f;
#pragma unroll
  for (int j = 0; j < 8; j++) part = fmaf(fmaxf(a2[j], 0.f), W3[d0 + j], part);
  sred[wu][lane] = part;
  __syncthreads();
  if (wu == 0 && valid)
    out[n] = sred[0][lane] + sred[1][lane] + sred[2][lane] + sred[3][lane] + b3[0];
}

// ---------------- host launch ----------------

extern "C" void kernel_launch(void* const* d_in, const int* in_sizes, int n_in,
                              void* d_out, int out_size, void* d_ws, size_t ws_size,
                              hipStream_t stream) {
  const float* x      = (const float*)d_in[0];
  const float* ea     = (const float*)d_in[1];
  const int*   ei     = (const int*)d_in[2];
  const float* W_node = (const float*)d_in[3];
  const float* b_node = (const float*)d_in[4];
  // d_in[5], d_in[6]: W_edge/b_edge — unused by the reference output
  const float* W_lin0 = (const float*)d_in[7];
  const float* b_lin0 = (const float*)d_in[8];
  const float* W_att0 = (const float*)d_in[9];
  const float* b_att0 = (const float*)d_in[10];
  const float* W_sl   = (const float*)d_in[11];
  const float* b_sl   = (const float*)d_in[12];
  const float* W_sr   = (const float*)d_in[13];
  const float* W_gcn  = (const float*)d_in[14];
  const float* b_gcn  = (const float*)d_in[15];
  const float* bn_g   = (const float*)d_in[16];  // [3,64]
  const float* bn_b   = (const float*)d_in[17];
  const float* W_r1   = (const float*)d_in[18];
  const float* b_r1   = (const float*)d_in[19];
  const float* W_r2   = (const float*)d_in[20];
  const float* b_r2   = (const float*)d_in[21];
  const float* W_r3   = (const float*)d_in[22];
  const float* b_r3   = (const float*)d_in[23];
  float* out = (float*)d_out;

  char* ws = (char*)d_ws;
  size_t o = 0;
  auto alloc = [&](size_t bytes) -> void* {
    void* p = ws + o;
    o += (bytes + 255) & ~(size_t)255;
    return p;
  };
  int*    deg    = (int*)alloc(NODES * 4);
  int*    rowptr = (int*)alloc((NODES + 1) * 4);
  int*    cur    = (int*)alloc(NODES * 4);
  int*    part   = (int*)alloc(256 * 4);
  uint*   sa     = (uint*)alloc((size_t)EDGES * 4);
  float*  hA     = (float*)alloc((size_t)NODES * HD * 4);
  float*  hC     = (float*)alloc((size_t)NODES * HD * 4);
  __half* hB16   = (__half*)alloc((size_t)NODES * HD * 2);
  __half* hC16   = (__half*)alloc((size_t)NODES * HD * 2);
  __half* hD16   = (__half*)alloc((size_t)NODES * HD * 2);
  float*  cvec   = (float*)alloc(NODES * 4);
  float*  dvec   = (float*)alloc(NODES * 4);
  float*  dis    = (float*)alloc(NODES * 4);
  (void)ws_size; (void)in_sizes; (void)n_in; (void)out_size;

  const int EB  = (EDGES + 255) / 256;
  const int NT  = (NODES + 63) / 64;     // 64 nodes/block
  const int NBW = (NODES + 3) / 4;       // wave-per-node (4 waves/block)

  hipMemsetAsync(deg, 0, NODES * 4, stream);
  k_hist<<<EB, 256, 0, stream>>>(ei, deg);
  k_scan1<<<NCHUNK, 256, 0, stream>>>(deg, part);
  k_scan2<<<1, 64, 0, stream>>>(part);
  k_scan3<<<NCHUNK, 256, 0, stream>>>(deg, part, rowptr, cur, dis);

  k_lin0<<<NT, 256, 0, stream>>>(x, W_node, b_node, W_lin0, b_lin0, W_att0,
                                 hA, hB16, cvec, dvec);
  k_fillatt<<<EB, 256, 0, stream>>>(ei, ea, cvec, dvec, W_att0, b_att0, cur, sa);
  k_agg_att<<<NBW, 256, 0, stream>>>(sa, rowptr, hA, hB16,
                                     bn_g + 0 * HD, bn_b + 0 * HD, hC, hC16);
  // fused mean-gather + SAGE + GCN pre-GEMM: t -> hA, hBp -> hD16
  k_msage<<<NT, 256, 0, stream>>>(sa, rowptr, hC, hC16, W_sl, b_sl, W_sr, W_gcn,
                                  bn_g + 1 * HD, bn_b + 1 * HD, dis, hA, hD16);
  // fused GCN aggregation + regressor -> out
  k_gcnreg<<<NT, 256, 0, stream>>>(sa, rowptr, dis, hA, hD16, b_gcn,
                                   bn_g + 2 * HD, bn_b + 2 * HD,
                                   W_r1, b_r1, W_r2, b_r2, W_r3, b_r3, out);
}

// Round 14
// 308.901 us; speedup vs baseline: 1.2083x; 1.0124x over previous
//
#include <hip/hip_runtime.h>
#include <hip/hip_fp16.h>
#include <math.h>

#define NODES 100000
#define EDGES 1250000
#define HD 64
#define NFD 16
#define CHUNK 1024
#define NCHUNK ((NODES + CHUNK - 1) / CHUNK)
#define BN_INV 0.9999950000374996f  // 1/sqrt(1+1e-5)
#define LP 65  // LDS row pitch: 65 % 32 == 1 -> 2-way bank aliasing (free)
#define SRCMASK 0x1FFFFu
#define WSCALE (1.0f / 32768.0f)

// ---------------- graph build ----------------

__global__ void k_hist(const int* __restrict__ ei, int* __restrict__ deg) {
  int e = blockIdx.x * blockDim.x + threadIdx.x;
  if (e < EDGES) atomicAdd(&deg[ei[EDGES + e]], 1);
}

__global__ void k_scan1(const int* __restrict__ deg, int* __restrict__ part) {
  __shared__ int lds[256];
  int t = threadIdx.x, b = blockIdx.x;
  int base = b * CHUNK + t * 4;
  int s = 0;
#pragma unroll
  for (int m = 0; m < 4; m++) { int i = base + m; if (i < NODES) s += deg[i]; }
  lds[t] = s; __syncthreads();
  for (int off = 128; off > 0; off >>= 1) {
    if (t < off) lds[t] += lds[t + off];
    __syncthreads();
  }
  if (t == 0) part[b] = lds[0];
}

__global__ void k_scan2(int* __restrict__ part) {
  if (threadIdx.x == 0 && blockIdx.x == 0) {
    int run = 0;
    for (int c = 0; c < NCHUNK; c++) { int v = part[c]; part[c] = run; run += v; }
  }
}

__global__ void k_scan3(const int* __restrict__ deg, const int* __restrict__ part,
                        int* __restrict__ rowptr, int* __restrict__ cur,
                        float* __restrict__ dis) {
  __shared__ int lds[256];
  int t = threadIdx.x, b = blockIdx.x;
  int base = b * CHUNK + t * 4;
  int dl[4]; int s = 0;
#pragma unroll
  for (int m = 0; m < 4; m++) { int i = base + m; dl[m] = (i < NODES) ? deg[i] : 0; s += dl[m]; }
  lds[t] = s; __syncthreads();
  for (int off = 1; off < 256; off <<= 1) {
    int add = (t >= off) ? lds[t - off] : 0;
    __syncthreads();
    lds[t] += add;
    __syncthreads();
  }
  int run = part[b] + lds[t] - s;  // exclusive prefix for this thread
#pragma unroll
  for (int m = 0; m < 4; m++) {
    int i = base + m;
    if (i < NODES) {
      rowptr[i] = run; cur[i] = run;
      dis[i] = 1.0f / sqrtf((float)(dl[m] + 1));  // GCN: indeg + self-loop
    }
    run += dl[m];
  }
  if (b == 0 && t == 0) rowptr[NODES] = EDGES;
}

// attention coeff in ORIGINAL edge order; packed 4B scatter: (q15(a)<<17)|src
__global__ void k_fillatt(const int* __restrict__ ei, const float* __restrict__ ea,
                          const float* __restrict__ cvec, const float* __restrict__ dvec,
                          const float* __restrict__ Wa, const float* __restrict__ ba,
                          int* __restrict__ cur, uint* __restrict__ sa) {
  int e = blockIdx.x * blockDim.x + threadIdx.x;
  if (e >= EDGES) return;
  int s = ei[e], d = ei[EDGES + e];
  float alin = cvec[d] + dvec[s] + ea[3 * e] * Wa[128] + ea[3 * e + 1] * Wa[129] +
               ea[3 * e + 2] * Wa[130] + ba[0];
  float lr = alin >= 0.f ? alin : 0.01f * alin;
  float a = 1.f / (1.f + expf(-lr));
  uint q = min((int)(a * 32768.f + 0.5f), 32767);
  int p = atomicAdd(&cur[d], 1);
  sa[p] = (q << 17) | (uint)s;
}

// ---------------- fp16 helpers ----------------

__device__ __forceinline__ void store16h(__half* dst, const float* v) {
  uint u[8];
#pragma unroll
  for (int j = 0; j < 8; j++) {
    __half2 h = __float22half2_rn(make_float2(v[2 * j], v[2 * j + 1]));
    u[j] = *reinterpret_cast<uint*>(&h);
  }
  uint4* o = (uint4*)dst;
  o[0] = make_uint4(u[0], u[1], u[2], u[3]);
  o[1] = make_uint4(u[4], u[5], u[6], u[7]);
}

__device__ __forceinline__ float4 h4tof4(uint2 u) {
  float2 fa = __half22float2(*reinterpret_cast<__half2*>(&u.x));
  float2 fb = __half22float2(*reinterpret_cast<__half2*>(&u.y));
  return make_float4(fa.x, fa.y, fb.x, fb.y);
}

// one 16-edge gather step (4 edge slots x 16 col-lanes), fp16 rows, packed sa
__device__ __forceinline__ void gstep(const __half* __restrict__ tab,
                                      const uint* __restrict__ sa,
                                      int m, int end, int last, int sub, int col,
                                      bool weighted,
                                      float4& A0, float4& A1, float4& A2, float4& A3) {
  int e0 = m + sub, e1 = e0 + 4, e2 = e0 + 8, e3 = e0 + 12;
  uint s0 = sa[min(e0, last)], s1 = sa[min(e1, last)];
  uint s2 = sa[min(e2, last)], s3 = sa[min(e3, last)];
  float w0 = (e0 < end) ? (weighted ? (float)(s0 >> 17) * WSCALE : 1.f) : 0.f;
  float w1 = (e1 < end) ? (weighted ? (float)(s1 >> 17) * WSCALE : 1.f) : 0.f;
  float w2 = (e2 < end) ? (weighted ? (float)(s2 >> 17) * WSCALE : 1.f) : 0.f;
  float w3 = (e3 < end) ? (weighted ? (float)(s3 >> 17) * WSCALE : 1.f) : 0.f;
  uint2 u0 = *((const uint2*)(tab + (size_t)(s0 & SRCMASK) * HD) + col);
  uint2 u1 = *((const uint2*)(tab + (size_t)(s1 & SRCMASK) * HD) + col);
  uint2 u2 = *((const uint2*)(tab + (size_t)(s2 & SRCMASK) * HD) + col);
  uint2 u3 = *((const uint2*)(tab + (size_t)(s3 & SRCMASK) * HD) + col);
  {
    float4 f = h4tof4(u0);
    A0.x = fmaf(w0, f.x, A0.x); A0.y = fmaf(w0, f.y, A0.y);
    A0.z = fmaf(w0, f.z, A0.z); A0.w = fmaf(w0, f.w, A0.w);
  }
  {
    float4 f = h4tof4(u1);
    A1.x = fmaf(w1, f.x, A1.x); A1.y = fmaf(w1, f.y, A1.y);
    A1.z = fmaf(w1, f.z, A1.z); A1.w = fmaf(w1, f.w, A1.w);
  }
  {
    float4 f = h4tof4(u2);
    A2.x = fmaf(w2, f.x, A2.x); A2.y = fmaf(w2, f.y, A2.y);
    A2.z = fmaf(w2, f.z, A2.z); A2.w = fmaf(w2, f.w, A2.w);
  }
  {
    float4 f = h4tof4(u3);
    A3.x = fmaf(w3, f.x, A3.x); A3.y = fmaf(w3, f.y, A3.y);
    A3.z = fmaf(w3, f.z, A3.z); A3.w = fmaf(w3, f.w, A3.w);
  }
}

__device__ __forceinline__ float4 red4(float4 a0, float4 a1, float4 a2, float4 a3) {
  float4 r;
  r.x = (a0.x + a1.x) + (a2.x + a3.x);
  r.y = (a0.y + a1.y) + (a2.y + a3.y);
  r.z = (a0.z + a1.z) + (a2.z + a3.z);
  r.w = (a0.w + a1.w) + (a2.w + a3.w);
#pragma unroll
  for (int off = 16; off <= 32; off <<= 1) {
    r.x += __shfl_xor(r.x, off); r.y += __shfl_xor(r.y, off);
    r.z += __shfl_xor(r.z, off); r.w += __shfl_xor(r.w, off);
  }
  return r;
}

#define AGG_BODY16(TABLE, WEIGHTED)                                              \
  float4 acc0 = make_float4(0.f, 0.f, 0.f, 0.f);                                 \
  float4 acc1 = make_float4(0.f, 0.f, 0.f, 0.f);                                 \
  float4 acc2 = make_float4(0.f, 0.f, 0.f, 0.f);                                 \
  float4 acc3 = make_float4(0.f, 0.f, 0.f, 0.f);                                 \
  int last = end - 1;                                                            \
  for (int m = start; m < end; m += 16)                                          \
    gstep(TABLE, sa, m, end, last, sub, col, WEIGHTED, acc0, acc1, acc2, acc3);  \
  float4 accr = red4(acc0, acc1, acc2, acc3);

// ---------------- kernels ----------------

// lin0: h = x@Wn + bn -> hA, LDS ; h0 = h@Wl + bl -> hB16 ; cvec/dvec dots
__global__ __launch_bounds__(256) void k_lin0(
    const float* __restrict__ x,
    const float* __restrict__ Wn, const float* __restrict__ bn,
    const float* __restrict__ Wl, const float* __restrict__ bl,
    const float* __restrict__ Wa,
    float* __restrict__ hA, __half* __restrict__ hB16,
    float* __restrict__ cvec, float* __restrict__ dvec) {
  __shared__ float sh[64 * LP];
  __shared__ float sc[4][64], sd[4][64];
  int slot = threadIdx.x & 63;
  int cc = __builtin_amdgcn_readfirstlane(threadIdx.x >> 6);
  int c0 = cc * 16;
  int n0 = blockIdx.x * 64 + slot;
  bool valid = n0 < NODES;
  int n = valid ? n0 : NODES - 1;
  const float4* xr = (const float4*)(x + (size_t)n * NFD);
  float acc[16];
#pragma unroll
  for (int j = 0; j < 16; j++) acc[j] = bn[c0 + j];
#pragma unroll
  for (int q = 0; q < 4; q++) {
    float4 xa = xr[q];
    float xs[4] = {xa.x, xa.y, xa.z, xa.w};
#pragma unroll
    for (int t = 0; t < 4; t++)
#pragma unroll
      for (int j = 0; j < 16; j++)
        acc[j] = fmaf(xs[t], Wn[(q * 4 + t) * HD + c0 + j], acc[j]);
  }
#pragma unroll
  for (int j = 0; j < 16; j++) sh[slot * LP + c0 + j] = acc[j];
  if (valid) {
    float4* o = (float4*)(hA + (size_t)n * HD + c0);
    o[0] = make_float4(acc[0], acc[1], acc[2], acc[3]);
    o[1] = make_float4(acc[4], acc[5], acc[6], acc[7]);
    o[2] = make_float4(acc[8], acc[9], acc[10], acc[11]);
    o[3] = make_float4(acc[12], acc[13], acc[14], acc[15]);
  }
  __syncthreads();
  float a2[16];
#pragma unroll
  for (int j = 0; j < 16; j++) a2[j] = bl[c0 + j];
#pragma unroll 8
  for (int k = 0; k < 64; k++) {
    float hk = sh[slot * LP + k];
#pragma unroll
    for (int j = 0; j < 16; j++)
      a2[j] = fmaf(hk, Wl[k * HD + c0 + j], a2[j]);
  }
  float cn = 0.f, dn = 0.f;
#pragma unroll
  for (int j = 0; j < 16; j++) {
    cn = fmaf(a2[j], Wa[c0 + j], cn);
    dn = fmaf(a2[j], Wa[64 + c0 + j], dn);
  }
  if (valid) store16h(hB16 + (size_t)n * HD + c0, a2);
  sc[cc][slot] = cn;
  sd[cc][slot] = dn;
  __syncthreads();
  if (cc == 0 && valid) {
    cvec[n] = sc[0][slot] + sc[1][slot] + sc[2][slot] + sc[3][slot];
    dvec[n] = sd[0][slot] + sd[1][slot] + sd[2][slot] + sd[3][slot];
  }
}

// layer0 aggregation: gather hB16 (weighted), write hC (fp32) + hC16
__global__ __launch_bounds__(256) void k_agg_att(
    const uint* __restrict__ sa, const int* __restrict__ rowptr,
    const float* __restrict__ hA, const __half* __restrict__ hB16,
    const float* __restrict__ g, const float* __restrict__ bt,
    float* __restrict__ hC, __half* __restrict__ hC16) {
  int lane = threadIdx.x & 63;
  int node = __builtin_amdgcn_readfirstlane(blockIdx.x * 4 + (threadIdx.x >> 6));
  if (node >= NODES) return;
  int start = rowptr[node], end = rowptr[node + 1];
  int sub = lane >> 4, col = lane & 15;
  float4 gg = ((const float4*)g)[col];
  float4 bb = ((const float4*)bt)[col];
  float4 ha = *((const float4*)(hA + (size_t)node * HD) + col);
  AGG_BODY16(hB16, true)
  if (lane < 16) {
    float4 v;
    v.x = fmaxf(accr.x * (gg.x * BN_INV) + bb.x, 0.f) + ha.x;
    v.y = fmaxf(accr.y * (gg.y * BN_INV) + bb.y, 0.f) + ha.y;
    v.z = fmaxf(accr.z * (gg.z * BN_INV) + bb.z, 0.f) + ha.z;
    v.w = fmaxf(accr.w * (gg.w * BN_INV) + bb.w, 0.f) + ha.w;
    *((float4*)(hC + (size_t)node * HD) + col) = v;
    __half2 p0 = __float22half2_rn(make_float2(v.x, v.y));
    __half2 p1 = __float22half2_rn(make_float2(v.z, v.w));
    uint2 u;
    u.x = *reinterpret_cast<uint*>(&p0);
    u.y = *reinterpret_cast<uint*>(&p1);
    *((uint2*)(hC16 + (size_t)node * HD) + col) = u;
  }
}

// mean aggregation, wave-per-node: gather hC16 -> fp16 mean rows (hM16)
__global__ __launch_bounds__(256) void k_agg_mean16(
    const uint* __restrict__ sa, const int* __restrict__ rowptr,
    const __half* __restrict__ hC16, __half* __restrict__ hM16) {
  int lane = threadIdx.x & 63;
  int node = __builtin_amdgcn_readfirstlane(blockIdx.x * 4 + (threadIdx.x >> 6));
  if (node >= NODES) return;
  int start = rowptr[node], end = rowptr[node + 1];
  int sub = lane >> 4, col = lane & 15;
  AGG_BODY16(hC16, false)
  if (lane < 16) {
    float rdeg = 1.f / fmaxf((float)(end - start), 1.f);
    __half2 p0 = __float22half2_rn(make_float2(accr.x * rdeg, accr.y * rdeg));
    __half2 p1 = __float22half2_rn(make_float2(accr.z * rdeg, accr.w * rdeg));
    uint2 u;
    u.x = *reinterpret_cast<uint*>(&p0);
    u.y = *reinterpret_cast<uint*>(&p1);
    *((uint2*)(hM16 + (size_t)node * HD) + col) = u;
  }
}

// SAGE + GCN pre-GEMM (GEMM-only tile kernel):
// t = relu(BN1(hM@Wsl + hC@Wsr + bsl)) + hC -> hA ; hD16 = dis*(t@Wg)
__global__ __launch_bounds__(256) void k_sagegcn(
    const __half* __restrict__ hM16, const float* __restrict__ hC,
    const float* __restrict__ Wl, const float* __restrict__ bl,
    const float* __restrict__ Wr, const float* __restrict__ Wg,
    const float* __restrict__ g, const float* __restrict__ bt,
    const float* __restrict__ dis,
    float* __restrict__ hA, __half* __restrict__ hD16) {
  __shared__ float sh[64 * LP];
  int slot = threadIdx.x & 63;
  int cc = __builtin_amdgcn_readfirstlane(threadIdx.x >> 6);
  int c0 = cc * 16;
  int n0 = blockIdx.x * 64 + slot;
  bool valid = n0 < NODES;
  int n = valid ? n0 : NODES - 1;
  // stage mean row chunk (16 halves) into LDS as fp32
  {
    const uint4* mp = (const uint4*)(hM16 + (size_t)n * HD + c0);
    uint4 m0 = mp[0], m1 = mp[1];
    uint mm[8] = {m0.x, m0.y, m0.z, m0.w, m1.x, m1.y, m1.z, m1.w};
#pragma unroll
    for (int j = 0; j < 8; j++) {
      float2 f = __half22float2(*reinterpret_cast<__half2*>(&mm[j]));
      sh[slot * LP + c0 + 2 * j] = f.x;
      sh[slot * LP + c0 + 2 * j + 1] = f.y;
    }
  }
  __syncthreads();
  const float4* cr = (const float4*)(hC + (size_t)n * HD);
  float acc[16];
#pragma unroll
  for (int j = 0; j < 16; j++) acc[j] = bl[c0 + j];
#pragma unroll 8
  for (int k = 0; k < 64; k++) {
    float mk = sh[slot * LP + k];
#pragma unroll
    for (int j = 0; j < 16; j++)
      acc[j] = fmaf(mk, Wl[k * HD + c0 + j], acc[j]);
  }
#pragma unroll 4
  for (int q = 0; q < 16; q++) {
    float4 ac = cr[q];
    float cs[4] = {ac.x, ac.y, ac.z, ac.w};
#pragma unroll
    for (int t = 0; t < 4; t++)
#pragma unroll
      for (int j = 0; j < 16; j++)
        acc[j] = fmaf(cs[t], Wr[(q * 4 + t) * HD + c0 + j], acc[j]);
  }
  float tv[16];
  {
    float4 r0 = cr[cc * 4 + 0], r1 = cr[cc * 4 + 1], r2 = cr[cc * 4 + 2], r3 = cr[cc * 4 + 3];
    float rv[16] = {r0.x, r0.y, r0.z, r0.w, r1.x, r1.y, r1.z, r1.w,
                    r2.x, r2.y, r2.z, r2.w, r3.x, r3.y, r3.z, r3.w};
#pragma unroll
    for (int j = 0; j < 16; j++)
      tv[j] = fmaxf(acc[j] * (g[c0 + j] * BN_INV) + bt[c0 + j], 0.f) + rv[j];
  }
  __syncthreads();  // mean rows fully consumed -> safe to overwrite
#pragma unroll
  for (int j = 0; j < 16; j++) sh[slot * LP + c0 + j] = tv[j];
  if (valid) {
    float4* o = (float4*)(hA + (size_t)n * HD + c0);
    o[0] = make_float4(tv[0], tv[1], tv[2], tv[3]);
    o[1] = make_float4(tv[4], tv[5], tv[6], tv[7]);
    o[2] = make_float4(tv[8], tv[9], tv[10], tv[11]);
    o[3] = make_float4(tv[12], tv[13], tv[14], tv[15]);
  }
  __syncthreads();
  float di = dis[n];
  float a2[16];
#pragma unroll
  for (int j = 0; j < 16; j++) a2[j] = 0.f;
#pragma unroll 8
  for (int k = 0; k < 64; k++) {
    float tk = sh[slot * LP + k];
#pragma unroll
    for (int j = 0; j < 16; j++)
      a2[j] = fmaf(tk, Wg[k * HD + c0 + j], a2[j]);
  }
#pragma unroll
  for (int j = 0; j < 16; j++) a2[j] *= di;
  if (valid) store16h(hD16 + (size_t)n * HD + c0, a2);
}

// FUSED GCN aggregation (gather hD16) + regressor head -> out. 256 threads.
__global__ __launch_bounds__(256) void k_gcnreg(
    const uint* __restrict__ sa, const int* __restrict__ rowptr,
    const float* __restrict__ dis,
    const float* __restrict__ hA,     // t (residual ident)
    const __half* __restrict__ hD16,  // fp16 gather + self table
    const float* __restrict__ bg,
    const float* __restrict__ g, const float* __restrict__ bt,
    const float* __restrict__ W1, const float* __restrict__ b1,
    const float* __restrict__ W2, const float* __restrict__ b2,
    const float* __restrict__ W3, const float* __restrict__ b3,
    float* __restrict__ out) {
  __shared__ float sh[64 * LP];
  __shared__ float sred[4][64];
  int lane = threadIdx.x & 63;
  int wu = __builtin_amdgcn_readfirstlane(threadIdx.x >> 6);
  int sub = lane >> 4, col = lane & 15;
  int nbase = blockIdx.x * 64;
  float4 gg = ((const float4*)g)[col];
  float4 bb = ((const float4*)bt)[col];
  float4 bgv = ((const float4*)bg)[col];
  // phase 1: gcn-gather + epilogue -> layer2 output rows in LDS
  for (int i = 0; i < 16; i++) {
    int slot = wu * 16 + i;
    int nn = min(nbase + slot, NODES - 1);
    int start = rowptr[nn], end = rowptr[nn + 1];
    float di = dis[nn];
    float4 sv = h4tof4(*((const uint2*)(hD16 + (size_t)nn * HD) + col));  // self
    float4 ha = *((const float4*)(hA + (size_t)nn * HD) + col);
    AGG_BODY16(hD16, false)
    if (lane < 16) {
      sh[slot * LP + col * 4 + 0] =
          fmaxf((di * (accr.x + sv.x) + bgv.x) * (gg.x * BN_INV) + bb.x, 0.f) + ha.x;
      sh[slot * LP + col * 4 + 1] =
          fmaxf((di * (accr.y + sv.y) + bgv.y) * (gg.y * BN_INV) + bb.y, 0.f) + ha.y;
      sh[slot * LP + col * 4 + 2] =
          fmaxf((di * (accr.z + sv.z) + bgv.z) * (gg.z * BN_INV) + bb.z, 0.f) + ha.z;
      sh[slot * LP + col * 4 + 3] =
          fmaxf((di * (accr.w + sv.w) + bgv.w) * (gg.w * BN_INV) + bb.w, 0.f) + ha.w;
    }
  }
  __syncthreads();
  // phase 2: regressor GEMM chain from LDS
  int c0 = wu * 16;
  int n0 = nbase + lane;
  bool valid = n0 < NODES;
  int n = valid ? n0 : NODES - 1;
  float acc[16];
#pragma unroll
  for (int j = 0; j < 16; j++) acc[j] = b1[c0 + j];
#pragma unroll 8
  for (int k = 0; k < 64; k++) {
    float rk = sh[lane * LP + k];
#pragma unroll
    for (int j = 0; j < 16; j++)
      acc[j] = fmaf(rk, W1[k * HD + c0 + j], acc[j]);
  }
  float t1v[16];
#pragma unroll
  for (int j = 0; j < 16; j++) t1v[j] = fmaxf(acc[j], 0.f);
  __syncthreads();  // layer2 rows consumed -> overwrite with t1
#pragma unroll
  for (int j = 0; j < 16; j++) sh[lane * LP + c0 + j] = t1v[j];
  __syncthreads();
  int d0 = wu * 8;
  float a2[8];
#pragma unroll
  for (int j = 0; j < 8; j++) a2[j] = b2[d0 + j];
#pragma unroll 8
  for (int k = 0; k < 64; k++) {
    float tk = sh[lane * LP + k];
#pragma unroll
    for (int j = 0; j < 8; j++)
      a2[j] = fmaf(tk, W2[k * 32 + d0 + j], a2[j]);
  }
  float part = 0.f;
#pragma unroll
  for (int j = 0; j < 8; j++) part = fmaf(fmaxf(a2[j], 0.f), W3[d0 + j], part);
  sred[wu][lane] = part;
  __syncthreads();
  if (wu == 0 && valid)
    out[n] = sred[0][lane] + sred[1][lane] + sred[2][lane] + sred[3][lane] + b3[0];
}

// ---------------- host launch ----------------

extern "C" void kernel_launch(void* const* d_in, const int* in_sizes, int n_in,
                              void* d_out, int out_size, void* d_ws, size_t ws_size,
                              hipStream_t stream) {
  const float* x      = (const float*)d_in[0];
  const float* ea     = (const float*)d_in[1];
  const int*   ei     = (const int*)d_in[2];
  const float* W_node = (const float*)d_in[3];
  const float* b_node = (const float*)d_in[4];
  // d_in[5], d_in[6]: W_edge/b_edge — unused by the reference output
  const float* W_lin0 = (const float*)d_in[7];
  const float* b_lin0 = (const float*)d_in[8];
  const float* W_att0 = (const float*)d_in[9];
  const float* b_att0 = (const float*)d_in[10];
  const float* W_sl   = (const float*)d_in[11];
  const float* b_sl   = (const float*)d_in[12];
  const float* W_sr   = (const float*)d_in[13];
  const float* W_gcn  = (const float*)d_in[14];
  const float* b_gcn  = (const float*)d_in[15];
  const float* bn_g   = (const float*)d_in[16];  // [3,64]
  const float* bn_b   = (const float*)d_in[17];
  const float* W_r1   = (const float*)d_in[18];
  const float* b_r1   = (const float*)d_in[19];
  const float* W_r2   = (const float*)d_in[20];
  const float* b_r2   = (const float*)d_in[21];
  const float* W_r3   = (const float*)d_in[22];
  const float* b_r3   = (const float*)d_in[23];
  float* out = (float*)d_out;

  char* ws = (char*)d_ws;
  size_t o = 0;
  auto alloc = [&](size_t bytes) -> void* {
    void* p = ws + o;
    o += (bytes + 255) & ~(size_t)255;
    return p;
  };
  int*    deg    = (int*)alloc(NODES * 4);
  int*    rowptr = (int*)alloc((NODES + 1) * 4);
  int*    cur    = (int*)alloc(NODES * 4);
  int*    part   = (int*)alloc(256 * 4);
  uint*   sa     = (uint*)alloc((size_t)EDGES * 4);
  float*  hA     = (float*)alloc((size_t)NODES * HD * 4);
  float*  hC     = (float*)alloc((size_t)NODES * HD * 4);
  __half* hB16   = (__half*)alloc((size_t)NODES * HD * 2);  // h0, then hM16
  __half* hC16   = (__half*)alloc((size_t)NODES * HD * 2);
  __half* hD16   = (__half*)alloc((size_t)NODES * HD * 2);
  float*  cvec   = (float*)alloc(NODES * 4);
  float*  dvec   = (float*)alloc(NODES * 4);
  float*  dis    = (float*)alloc(NODES * 4);
  (void)ws_size; (void)in_sizes; (void)n_in; (void)out_size;

  const int EB  = (EDGES + 255) / 256;
  const int NT  = (NODES + 63) / 64;     // 64 nodes/block
  const int NBW = (NODES + 3) / 4;       // wave-per-node (4 waves/block)

  hipMemsetAsync(deg, 0, NODES * 4, stream);
  k_hist<<<EB, 256, 0, stream>>>(ei, deg);
  k_scan1<<<NCHUNK, 256, 0, stream>>>(deg, part);
  k_scan2<<<1, 64, 0, stream>>>(part);
  k_scan3<<<NCHUNK, 256, 0, stream>>>(deg, part, rowptr, cur, dis);

  k_lin0<<<NT, 256, 0, stream>>>(x, W_node, b_node, W_lin0, b_lin0, W_att0,
                                 hA, hB16, cvec, dvec);
  k_fillatt<<<EB, 256, 0, stream>>>(ei, ea, cvec, dvec, W_att0, b_att0, cur, sa);
  k_agg_att<<<NBW, 256, 0, stream>>>(sa, rowptr, hA, hB16,
                                     bn_g + 0 * HD, bn_b + 0 * HD, hC, hC16);
  // hB16 (h0) dead -> reuse as fp16 mean table
  k_agg_mean16<<<NBW, 256, 0, stream>>>(sa, rowptr, hC16, hB16);
  // GEMM-only SAGE + GCN pre-GEMM: t -> hA, hBp -> hD16
  k_sagegcn<<<NT, 256, 0, stream>>>(hB16, hC, W_sl, b_sl, W_sr, W_gcn,
                                    bn_g + 1 * HD, bn_b + 1 * HD, dis, hA, hD16);
  // fused GCN aggregation + regressor -> out
  k_gcnreg<<<NT, 256, 0, stream>>>(sa, rowptr, dis, hA, hD16, b_gcn,
                                   bn_g + 2 * HD, bn_b + 2 * HD,
                                   W_r1, b_r1, W_r2, b_r2, W_r3, b_r3, out);
}

// Round 15
// 305.199 us; speedup vs baseline: 1.2230x; 1.0121x over previous
//
#include <hip/hip_runtime.h>
#include <hip/hip_fp16.h>
#include <math.h>

#define NODES 100000
#define EDGES 1250000
#define HD 64
#define NFD 16
#define CHUNK 1024
#define NCHUNK ((NODES + CHUNK - 1) / CHUNK)
#define BN_INV 0.9999950000374996f  // 1/sqrt(1+1e-5)
#define LP 65  // LDS row pitch: 65 % 32 == 1 -> 2-way bank aliasing (free)
#define SRCMASK 0x1FFFFu
#define WSCALE (1.0f / 32768.0f)

// ---------------- graph build ----------------

__global__ void k_hist(const int* __restrict__ ei, int* __restrict__ deg) {
  int e = blockIdx.x * blockDim.x + threadIdx.x;
  if (e < EDGES) atomicAdd(&deg[ei[EDGES + e]], 1);
}

__global__ void k_scan1(const int* __restrict__ deg, int* __restrict__ part) {
  __shared__ int lds[256];
  int t = threadIdx.x, b = blockIdx.x;
  int base = b * CHUNK + t * 4;
  int s = 0;
#pragma unroll
  for (int m = 0; m < 4; m++) { int i = base + m; if (i < NODES) s += deg[i]; }
  lds[t] = s; __syncthreads();
  for (int off = 128; off > 0; off >>= 1) {
    if (t < off) lds[t] += lds[t + off];
    __syncthreads();
  }
  if (t == 0) part[b] = lds[0];
}

__global__ void k_scan2(int* __restrict__ part) {
  if (threadIdx.x == 0 && blockIdx.x == 0) {
    int run = 0;
    for (int c = 0; c < NCHUNK; c++) { int v = part[c]; part[c] = run; run += v; }
  }
}

__global__ void k_scan3(const int* __restrict__ deg, const int* __restrict__ part,
                        int* __restrict__ rowptr, int* __restrict__ cur,
                        float* __restrict__ dis) {
  __shared__ int lds[256];
  int t = threadIdx.x, b = blockIdx.x;
  int base = b * CHUNK + t * 4;
  int dl[4]; int s = 0;
#pragma unroll
  for (int m = 0; m < 4; m++) { int i = base + m; dl[m] = (i < NODES) ? deg[i] : 0; s += dl[m]; }
  lds[t] = s; __syncthreads();
  for (int off = 1; off < 256; off <<= 1) {
    int add = (t >= off) ? lds[t - off] : 0;
    __syncthreads();
    lds[t] += add;
    __syncthreads();
  }
  int run = part[b] + lds[t] - s;  // exclusive prefix for this thread
#pragma unroll
  for (int m = 0; m < 4; m++) {
    int i = base + m;
    if (i < NODES) {
      rowptr[i] = run; cur[i] = run;
      dis[i] = 1.0f / sqrtf((float)(dl[m] + 1));  // GCN: indeg + self-loop
    }
    run += dl[m];
  }
  if (b == 0 && t == 0) rowptr[NODES] = EDGES;
}

// attention coeff in ORIGINAL edge order; packed 4B scatter: (q15(a)<<17)|src
__global__ void k_fillatt(const int* __restrict__ ei, const float* __restrict__ ea,
                          const float* __restrict__ cvec, const float* __restrict__ dvec,
                          const float* __restrict__ Wa, const float* __restrict__ ba,
                          int* __restrict__ cur, uint* __restrict__ sa) {
  int e = blockIdx.x * blockDim.x + threadIdx.x;
  if (e >= EDGES) return;
  int s = ei[e], d = ei[EDGES + e];
  float alin = cvec[d] + dvec[s] + ea[3 * e] * Wa[128] + ea[3 * e + 1] * Wa[129] +
               ea[3 * e + 2] * Wa[130] + ba[0];
  float lr = alin >= 0.f ? alin : 0.01f * alin;
  float a = 1.f / (1.f + expf(-lr));
  uint q = min((int)(a * 32768.f + 0.5f), 32767);
  int p = atomicAdd(&cur[d], 1);
  sa[p] = (q << 17) | (uint)s;
}

// ---------------- fp16 helpers ----------------

__device__ __forceinline__ void store16h(__half* dst, const float* v) {
  uint u[8];
#pragma unroll
  for (int j = 0; j < 8; j++) {
    __half2 h = __float22half2_rn(make_float2(v[2 * j], v[2 * j + 1]));
    u[j] = *reinterpret_cast<uint*>(&h);
  }
  uint4* o = (uint4*)dst;
  o[0] = make_uint4(u[0], u[1], u[2], u[3]);
  o[1] = make_uint4(u[4], u[5], u[6], u[7]);
}

__device__ __forceinline__ float4 h4tof4(uint2 u) {
  float2 fa = __half22float2(*reinterpret_cast<__half2*>(&u.x));
  float2 fb = __half22float2(*reinterpret_cast<__half2*>(&u.y));
  return make_float4(fa.x, fa.y, fb.x, fb.y);
}

// one 16-edge gather step (4 edge slots x 16 col-lanes), fp16 rows, packed sa
__device__ __forceinline__ void gstep(const __half* __restrict__ tab,
                                      const uint* __restrict__ sa,
                                      int m, int end, int last, int sub, int col,
                                      bool weighted,
                                      float4& A0, float4& A1, float4& A2, float4& A3) {
  int e0 = m + sub, e1 = e0 + 4, e2 = e0 + 8, e3 = e0 + 12;
  uint s0 = sa[min(e0, last)], s1 = sa[min(e1, last)];
  uint s2 = sa[min(e2, last)], s3 = sa[min(e3, last)];
  float w0 = (e0 < end) ? (weighted ? (float)(s0 >> 17) * WSCALE : 1.f) : 0.f;
  float w1 = (e1 < end) ? (weighted ? (float)(s1 >> 17) * WSCALE : 1.f) : 0.f;
  float w2 = (e2 < end) ? (weighted ? (float)(s2 >> 17) * WSCALE : 1.f) : 0.f;
  float w3 = (e3 < end) ? (weighted ? (float)(s3 >> 17) * WSCALE : 1.f) : 0.f;
  uint2 u0 = *((const uint2*)(tab + (size_t)(s0 & SRCMASK) * HD) + col);
  uint2 u1 = *((const uint2*)(tab + (size_t)(s1 & SRCMASK) * HD) + col);
  uint2 u2 = *((const uint2*)(tab + (size_t)(s2 & SRCMASK) * HD) + col);
  uint2 u3 = *((const uint2*)(tab + (size_t)(s3 & SRCMASK) * HD) + col);
  {
    float4 f = h4tof4(u0);
    A0.x = fmaf(w0, f.x, A0.x); A0.y = fmaf(w0, f.y, A0.y);
    A0.z = fmaf(w0, f.z, A0.z); A0.w = fmaf(w0, f.w, A0.w);
  }
  {
    float4 f = h4tof4(u1);
    A1.x = fmaf(w1, f.x, A1.x); A1.y = fmaf(w1, f.y, A1.y);
    A1.z = fmaf(w1, f.z, A1.z); A1.w = fmaf(w1, f.w, A1.w);
  }
  {
    float4 f = h4tof4(u2);
    A2.x = fmaf(w2, f.x, A2.x); A2.y = fmaf(w2, f.y, A2.y);
    A2.z = fmaf(w2, f.z, A2.z); A2.w = fmaf(w2, f.w, A2.w);
  }
  {
    float4 f = h4tof4(u3);
    A3.x = fmaf(w3, f.x, A3.x); A3.y = fmaf(w3, f.y, A3.y);
    A3.z = fmaf(w3, f.z, A3.z); A3.w = fmaf(w3, f.w, A3.w);
  }
}

__device__ __forceinline__ float4 red4(float4 a0, float4 a1, float4 a2, float4 a3) {
  float4 r;
  r.x = (a0.x + a1.x) + (a2.x + a3.x);
  r.y = (a0.y + a1.y) + (a2.y + a3.y);
  r.z = (a0.z + a1.z) + (a2.z + a3.z);
  r.w = (a0.w + a1.w) + (a2.w + a3.w);
#pragma unroll
  for (int off = 16; off <= 32; off <<= 1) {
    r.x += __shfl_xor(r.x, off); r.y += __shfl_xor(r.y, off);
    r.z += __shfl_xor(r.z, off); r.w += __shfl_xor(r.w, off);
  }
  return r;
}

#define AGG_BODY16(TABLE, WEIGHTED)                                              \
  float4 acc0 = make_float4(0.f, 0.f, 0.f, 0.f);                                 \
  float4 acc1 = make_float4(0.f, 0.f, 0.f, 0.f);                                 \
  float4 acc2 = make_float4(0.f, 0.f, 0.f, 0.f);                                 \
  float4 acc3 = make_float4(0.f, 0.f, 0.f, 0.f);                                 \
  int last = end - 1;                                                            \
  for (int m = start; m < end; m += 16)                                          \
    gstep(TABLE, sa, m, end, last, sub, col, WEIGHTED, acc0, acc1, acc2, acc3);  \
  float4 accr = red4(acc0, acc1, acc2, acc3);

// ---------------- kernels ----------------

// lin0: h = x@Wn + bn -> hA, LDS ; h0 = h@Wl + bl -> hB16 ; cvec/dvec dots
__global__ __launch_bounds__(256) void k_lin0(
    const float* __restrict__ x,
    const float* __restrict__ Wn, const float* __restrict__ bn,
    const float* __restrict__ Wl, const float* __restrict__ bl,
    const float* __restrict__ Wa,
    float* __restrict__ hA, __half* __restrict__ hB16,
    float* __restrict__ cvec, float* __restrict__ dvec) {
  __shared__ float sh[64 * LP];
  __shared__ float sc[4][64], sd[4][64];
  int slot = threadIdx.x & 63;
  int cc = __builtin_amdgcn_readfirstlane(threadIdx.x >> 6);
  int c0 = cc * 16;
  int n0 = blockIdx.x * 64 + slot;
  bool valid = n0 < NODES;
  int n = valid ? n0 : NODES - 1;
  const float4* xr = (const float4*)(x + (size_t)n * NFD);
  float acc[16];
#pragma unroll
  for (int j = 0; j < 16; j++) acc[j] = bn[c0 + j];
#pragma unroll
  for (int q = 0; q < 4; q++) {
    float4 xa = xr[q];
    float xs[4] = {xa.x, xa.y, xa.z, xa.w};
#pragma unroll
    for (int t = 0; t < 4; t++)
#pragma unroll
      for (int j = 0; j < 16; j++)
        acc[j] = fmaf(xs[t], Wn[(q * 4 + t) * HD + c0 + j], acc[j]);
  }
#pragma unroll
  for (int j = 0; j < 16; j++) sh[slot * LP + c0 + j] = acc[j];
  if (valid) {
    float4* o = (float4*)(hA + (size_t)n * HD + c0);
    o[0] = make_float4(acc[0], acc[1], acc[2], acc[3]);
    o[1] = make_float4(acc[4], acc[5], acc[6], acc[7]);
    o[2] = make_float4(acc[8], acc[9], acc[10], acc[11]);
    o[3] = make_float4(acc[12], acc[13], acc[14], acc[15]);
  }
  __syncthreads();
  float a2[16];
#pragma unroll
  for (int j = 0; j < 16; j++) a2[j] = bl[c0 + j];
#pragma unroll 8
  for (int k = 0; k < 64; k++) {
    float hk = sh[slot * LP + k];
#pragma unroll
    for (int j = 0; j < 16; j++)
      a2[j] = fmaf(hk, Wl[k * HD + c0 + j], a2[j]);
  }
  float cn = 0.f, dn = 0.f;
#pragma unroll
  for (int j = 0; j < 16; j++) {
    cn = fmaf(a2[j], Wa[c0 + j], cn);
    dn = fmaf(a2[j], Wa[64 + c0 + j], dn);
  }
  if (valid) store16h(hB16 + (size_t)n * HD + c0, a2);
  sc[cc][slot] = cn;
  sd[cc][slot] = dn;
  __syncthreads();
  if (cc == 0 && valid) {
    cvec[n] = sc[0][slot] + sc[1][slot] + sc[2][slot] + sc[3][slot];
    dvec[n] = sd[0][slot] + sd[1][slot] + sd[2][slot] + sd[3][slot];
  }
}

// layer0 aggregation: gather hB16 (weighted), write hC (fp32) + hC16
__global__ __launch_bounds__(256) void k_agg_att(
    const uint* __restrict__ sa, const int* __restrict__ rowptr,
    const float* __restrict__ hA, const __half* __restrict__ hB16,
    const float* __restrict__ g, const float* __restrict__ bt,
    float* __restrict__ hC, __half* __restrict__ hC16) {
  int lane = threadIdx.x & 63;
  int node = __builtin_amdgcn_readfirstlane(blockIdx.x * 4 + (threadIdx.x >> 6));
  if (node >= NODES) return;
  int start = rowptr[node], end = rowptr[node + 1];
  int sub = lane >> 4, col = lane & 15;
  float4 gg = ((const float4*)g)[col];
  float4 bb = ((const float4*)bt)[col];
  float4 ha = *((const float4*)(hA + (size_t)node * HD) + col);
  AGG_BODY16(hB16, true)
  if (lane < 16) {
    float4 v;
    v.x = fmaxf(accr.x * (gg.x * BN_INV) + bb.x, 0.f) + ha.x;
    v.y = fmaxf(accr.y * (gg.y * BN_INV) + bb.y, 0.f) + ha.y;
    v.z = fmaxf(accr.z * (gg.z * BN_INV) + bb.z, 0.f) + ha.z;
    v.w = fmaxf(accr.w * (gg.w * BN_INV) + bb.w, 0.f) + ha.w;
    *((float4*)(hC + (size_t)node * HD) + col) = v;
    __half2 p0 = __float22half2_rn(make_float2(v.x, v.y));
    __half2 p1 = __float22half2_rn(make_float2(v.z, v.w));
    uint2 u;
    u.x = *reinterpret_cast<uint*>(&p0);
    u.y = *reinterpret_cast<uint*>(&p1);
    *((uint2*)(hC16 + (size_t)node * HD) + col) = u;
  }
}

// mean aggregation, wave-per-node: gather hC16 -> fp16 mean rows (hM16)
__global__ __launch_bounds__(256) void k_agg_mean16(
    const uint* __restrict__ sa, const int* __restrict__ rowptr,
    const __half* __restrict__ hC16, __half* __restrict__ hM16) {
  int lane = threadIdx.x & 63;
  int node = __builtin_amdgcn_readfirstlane(blockIdx.x * 4 + (threadIdx.x >> 6));
  if (node >= NODES) return;
  int start = rowptr[node], end = rowptr[node + 1];
  int sub = lane >> 4, col = lane & 15;
  AGG_BODY16(hC16, false)
  if (lane < 16) {
    float rdeg = 1.f / fmaxf((float)(end - start), 1.f);
    __half2 p0 = __float22half2_rn(make_float2(accr.x * rdeg, accr.y * rdeg));
    __half2 p1 = __float22half2_rn(make_float2(accr.z * rdeg, accr.w * rdeg));
    uint2 u;
    u.x = *reinterpret_cast<uint*>(&p0);
    u.y = *reinterpret_cast<uint*>(&p1);
    *((uint2*)(hM16 + (size_t)node * HD) + col) = u;
  }
}

// SAGE + GCN pre-GEMM (GEMM-only tile kernel):
// t = relu(BN1(hM@Wsl + hC@Wsr + bsl)) + hC -> hA ; hD16 = dis*(t@Wg)
__global__ __launch_bounds__(256) void k_sagegcn(
    const __half* __restrict__ hM16, const float* __restrict__ hC,
    const float* __restrict__ Wl, const float* __restrict__ bl,
    const float* __restrict__ Wr, const float* __restrict__ Wg,
    const float* __restrict__ g, const float* __restrict__ bt,
    const float* __restrict__ dis,
    float* __restrict__ hA, __half* __restrict__ hD16) {
  __shared__ float sh[64 * LP];
  int slot = threadIdx.x & 63;
  int cc = __builtin_amdgcn_readfirstlane(threadIdx.x >> 6);
  int c0 = cc * 16;
  int n0 = blockIdx.x * 64 + slot;
  bool valid = n0 < NODES;
  int n = valid ? n0 : NODES - 1;
  // stage mean row chunk (16 halves) into LDS as fp32
  {
    const uint4* mp = (const uint4*)(hM16 + (size_t)n * HD + c0);
    uint4 m0 = mp[0], m1 = mp[1];
    uint mm[8] = {m0.x, m0.y, m0.z, m0.w, m1.x, m1.y, m1.z, m1.w};
#pragma unroll
    for (int j = 0; j < 8; j++) {
      float2 f = __half22float2(*reinterpret_cast<__half2*>(&mm[j]));
      sh[slot * LP + c0 + 2 * j] = f.x;
      sh[slot * LP + c0 + 2 * j + 1] = f.y;
    }
  }
  __syncthreads();
  const float4* cr = (const float4*)(hC + (size_t)n * HD);
  float acc[16];
#pragma unroll
  for (int j = 0; j < 16; j++) acc[j] = bl[c0 + j];
#pragma unroll 8
  for (int k = 0; k < 64; k++) {
    float mk = sh[slot * LP + k];
#pragma unroll
    for (int j = 0; j < 16; j++)
      acc[j] = fmaf(mk, Wl[k * HD + c0 + j], acc[j]);
  }
#pragma unroll 4
  for (int q = 0; q < 16; q++) {
    float4 ac = cr[q];
    float cs[4] = {ac.x, ac.y, ac.z, ac.w};
#pragma unroll
    for (int t = 0; t < 4; t++)
#pragma unroll
      for (int j = 0; j < 16; j++)
        acc[j] = fmaf(cs[t], Wr[(q * 4 + t) * HD + c0 + j], acc[j]);
  }
  float tv[16];
  {
    float4 r0 = cr[cc * 4 + 0], r1 = cr[cc * 4 + 1], r2 = cr[cc * 4 + 2], r3 = cr[cc * 4 + 3];
    float rv[16] = {r0.x, r0.y, r0.z, r0.w, r1.x, r1.y, r1.z, r1.w,
                    r2.x, r2.y, r2.z, r2.w, r3.x, r3.y, r3.z, r3.w};
#pragma unroll
    for (int j = 0; j < 16; j++)
      tv[j] = fmaxf(acc[j] * (g[c0 + j] * BN_INV) + bt[c0 + j], 0.f) + rv[j];
  }
  __syncthreads();  // mean rows fully consumed -> safe to overwrite
#pragma unroll
  for (int j = 0; j < 16; j++) sh[slot * LP + c0 + j] = tv[j];
  if (valid) {
    float4* o = (float4*)(hA + (size_t)n * HD + c0);
    o[0] = make_float4(tv[0], tv[1], tv[2], tv[3]);
    o[1] = make_float4(tv[4], tv[5], tv[6], tv[7]);
    o[2] = make_float4(tv[8], tv[9], tv[10], tv[11]);
    o[3] = make_float4(tv[12], tv[13], tv[14], tv[15]);
  }
  __syncthreads();
  float di = dis[n];
  float a2[16];
#pragma unroll
  for (int j = 0; j < 16; j++) a2[j] = 0.f;
#pragma unroll 8
  for (int k = 0; k < 64; k++) {
    float tk = sh[slot * LP + k];
#pragma unroll
    for (int j = 0; j < 16; j++)
      a2[j] = fmaf(tk, Wg[k * HD + c0 + j], a2[j]);
  }
#pragma unroll
  for (int j = 0; j < 16; j++) a2[j] *= di;
  if (valid) store16h(hD16 + (size_t)n * HD + c0, a2);
}

// GCN aggregation, wave-per-node: gather hD16 + full layer2 epilogue -> hO16
__global__ __launch_bounds__(256) void k_agg_gcn16(
    const uint* __restrict__ sa, const int* __restrict__ rowptr,
    const float* __restrict__ dis,
    const float* __restrict__ hA,     // t (residual ident, fp32)
    const __half* __restrict__ hD16,  // fp16 gather + self table
    const float* __restrict__ bg,
    const float* __restrict__ g, const float* __restrict__ bt,
    __half* __restrict__ hO16) {
  int lane = threadIdx.x & 63;
  int node = __builtin_amdgcn_readfirstlane(blockIdx.x * 4 + (threadIdx.x >> 6));
  if (node >= NODES) return;
  int start = rowptr[node], end = rowptr[node + 1];
  int sub = lane >> 4, col = lane & 15;
  float di = dis[node];
  float4 sv = h4tof4(*((const uint2*)(hD16 + (size_t)node * HD) + col));  // self
  float4 ha = *((const float4*)(hA + (size_t)node * HD) + col);
  float4 gg = ((const float4*)g)[col];
  float4 bb = ((const float4*)bt)[col];
  float4 bgv = ((const float4*)bg)[col];
  AGG_BODY16(hD16, false)
  if (lane < 16) {
    float4 v;
    v.x = fmaxf((di * (accr.x + sv.x) + bgv.x) * (gg.x * BN_INV) + bb.x, 0.f) + ha.x;
    v.y = fmaxf((di * (accr.y + sv.y) + bgv.y) * (gg.y * BN_INV) + bb.y, 0.f) + ha.y;
    v.z = fmaxf((di * (accr.z + sv.z) + bgv.z) * (gg.z * BN_INV) + bb.z, 0.f) + ha.z;
    v.w = fmaxf((di * (accr.w + sv.w) + bgv.w) * (gg.w * BN_INV) + bb.w, 0.f) + ha.w;
    __half2 p0 = __float22half2_rn(make_float2(v.x, v.y));
    __half2 p1 = __float22half2_rn(make_float2(v.z, v.w));
    uint2 u;
    u.x = *reinterpret_cast<uint*>(&p0);
    u.y = *reinterpret_cast<uint*>(&p1);
    *((uint2*)(hO16 + (size_t)node * HD) + col) = u;
  }
}

// regressor head (GEMM-only tile kernel): out = relu(relu(hO@W1+b1)@W2+b2)@W3+b3
__global__ __launch_bounds__(256) void k_reg(
    const __half* __restrict__ hO16,
    const float* __restrict__ W1, const float* __restrict__ b1,
    const float* __restrict__ W2, const float* __restrict__ b2,
    const float* __restrict__ W3, const float* __restrict__ b3,
    float* __restrict__ out) {
  __shared__ float sh[64 * LP];
  __shared__ float sred[4][64];
  int slot = threadIdx.x & 63;
  int cc = __builtin_amdgcn_readfirstlane(threadIdx.x >> 6);
  int c0 = cc * 16;
  int n0 = blockIdx.x * 64 + slot;
  bool valid = n0 < NODES;
  int n = valid ? n0 : NODES - 1;
  // stage fp16 row chunk into LDS as fp32
  {
    const uint4* mp = (const uint4*)(hO16 + (size_t)n * HD + c0);
    uint4 m0 = mp[0], m1 = mp[1];
    uint mm[8] = {m0.x, m0.y, m0.z, m0.w, m1.x, m1.y, m1.z, m1.w};
#pragma unroll
    for (int j = 0; j < 8; j++) {
      float2 f = __half22float2(*reinterpret_cast<__half2*>(&mm[j]));
      sh[slot * LP + c0 + 2 * j] = f.x;
      sh[slot * LP + c0 + 2 * j + 1] = f.y;
    }
  }
  __syncthreads();
  float acc[16];
#pragma unroll
  for (int j = 0; j < 16; j++) acc[j] = b1[c0 + j];
#pragma unroll 8
  for (int k = 0; k < 64; k++) {
    float rk = sh[slot * LP + k];
#pragma unroll
    for (int j = 0; j < 16; j++)
      acc[j] = fmaf(rk, W1[k * HD + c0 + j], acc[j]);
  }
  float t1v[16];
#pragma unroll
  for (int j = 0; j < 16; j++) t1v[j] = fmaxf(acc[j], 0.f);
  __syncthreads();  // input rows consumed -> overwrite with t1
#pragma unroll
  for (int j = 0; j < 16; j++) sh[slot * LP + c0 + j] = t1v[j];
  __syncthreads();
  int d0 = cc * 8;
  float a2[8];
#pragma unroll
  for (int j = 0; j < 8; j++) a2[j] = b2[d0 + j];
#pragma unroll 8
  for (int k = 0; k < 64; k++) {
    float tk = sh[slot * LP + k];
#pragma unroll
    for (int j = 0; j < 8; j++)
      a2[j] = fmaf(tk, W2[k * 32 + d0 + j], a2[j]);
  }
  float part = 0.f;
#pragma unroll
  for (int j = 0; j < 8; j++) part = fmaf(fmaxf(a2[j], 0.f), W3[d0 + j], part);
  sred[cc][slot] = part;
  __syncthreads();
  if (cc == 0 && valid)
    out[n] = sred[0][slot] + sred[1][slot] + sred[2][slot] + sred[3][slot] + b3[0];
}

// ---------------- host launch ----------------

extern "C" void kernel_launch(void* const* d_in, const int* in_sizes, int n_in,
                              void* d_out, int out_size, void* d_ws, size_t ws_size,
                              hipStream_t stream) {
  const float* x      = (const float*)d_in[0];
  const float* ea     = (const float*)d_in[1];
  const int*   ei     = (const int*)d_in[2];
  const float* W_node = (const float*)d_in[3];
  const float* b_node = (const float*)d_in[4];
  // d_in[5], d_in[6]: W_edge/b_edge — unused by the reference output
  const float* W_lin0 = (const float*)d_in[7];
  const float* b_lin0 = (const float*)d_in[8];
  const float* W_att0 = (const float*)d_in[9];
  const float* b_att0 = (const float*)d_in[10];
  const float* W_sl   = (const float*)d_in[11];
  const float* b_sl   = (const float*)d_in[12];
  const float* W_sr   = (const float*)d_in[13];
  const float* W_gcn  = (const float*)d_in[14];
  const float* b_gcn  = (const float*)d_in[15];
  const float* bn_g   = (const float*)d_in[16];  // [3,64]
  const float* bn_b   = (const float*)d_in[17];
  const float* W_r1   = (const float*)d_in[18];
  const float* b_r1   = (const float*)d_in[19];
  const float* W_r2   = (const float*)d_in[20];
  const float* b_r2   = (const float*)d_in[21];
  const float* W_r3   = (const float*)d_in[22];
  const float* b_r3   = (const float*)d_in[23];
  float* out = (float*)d_out;

  char* ws = (char*)d_ws;
  size_t o = 0;
  auto alloc = [&](size_t bytes) -> void* {
    void* p = ws + o;
    o += (bytes + 255) & ~(size_t)255;
    return p;
  };
  int*    deg    = (int*)alloc(NODES * 4);
  int*    rowptr = (int*)alloc((NODES + 1) * 4);
  int*    cur    = (int*)alloc(NODES * 4);
  int*    part   = (int*)alloc(256 * 4);
  uint*   sa     = (uint*)alloc((size_t)EDGES * 4);
  float*  hA     = (float*)alloc((size_t)NODES * HD * 4);
  float*  hC     = (float*)alloc((size_t)NODES * HD * 4);
  __half* hB16   = (__half*)alloc((size_t)NODES * HD * 2);  // h0, then hM16
  __half* hC16   = (__half*)alloc((size_t)NODES * HD * 2);  // hC, then layer2 out
  __half* hD16   = (__half*)alloc((size_t)NODES * HD * 2);
  float*  cvec   = (float*)alloc(NODES * 4);
  float*  dvec   = (float*)alloc(NODES * 4);
  float*  dis    = (float*)alloc(NODES * 4);
  (void)ws_size; (void)in_sizes; (void)n_in; (void)out_size;

  const int EB  = (EDGES + 255) / 256;
  const int NT  = (NODES + 63) / 64;     // 64 nodes/block
  const int NBW = (NODES + 3) / 4;       // wave-per-node (4 waves/block)

  hipMemsetAsync(deg, 0, NODES * 4, stream);
  k_hist<<<EB, 256, 0, stream>>>(ei, deg);
  k_scan1<<<NCHUNK, 256, 0, stream>>>(deg, part);
  k_scan2<<<1, 64, 0, stream>>>(part);
  k_scan3<<<NCHUNK, 256, 0, stream>>>(deg, part, rowptr, cur, dis);

  k_lin0<<<NT, 256, 0, stream>>>(x, W_node, b_node, W_lin0, b_lin0, W_att0,
                                 hA, hB16, cvec, dvec);
  k_fillatt<<<EB, 256, 0, stream>>>(ei, ea, cvec, dvec, W_att0, b_att0, cur, sa);
  k_agg_att<<<NBW, 256, 0, stream>>>(sa, rowptr, hA, hB16,
                                     bn_g + 0 * HD, bn_b + 0 * HD, hC, hC16);
  // hB16 (h0) dead -> reuse as fp16 mean table
  k_agg_mean16<<<NBW, 256, 0, stream>>>(sa, rowptr, hC16, hB16);
  // GEMM-only SAGE + GCN pre-GEMM: t -> hA, hBp -> hD16
  k_sagegcn<<<NT, 256, 0, stream>>>(hB16, hC, W_sl, b_sl, W_sr, W_gcn,
                                    bn_g + 1 * HD, bn_b + 1 * HD, dis, hA, hD16);
  // GCN aggregation (wave-per-node) -> layer2 rows into hC16 (dead)
  k_agg_gcn16<<<NBW, 256, 0, stream>>>(sa, rowptr, dis, hA, hD16, b_gcn,
                                       bn_g + 2 * HD, bn_b + 2 * HD, hC16);
  // regressor head from fp16 rows -> out
  k_reg<<<NT, 256, 0, stream>>>(hC16, W_r1, b_r1, W_r2, b_r2, W_r3, b_r3, out);
}

// Round 16
// 300.040 us; speedup vs baseline: 1.2440x; 1.0172x over previous
//
#include <hip/hip_runtime.h>
#include <hip/hip_fp16.h>
#include <math.h>

#define NODES 100000
#define EDGES 1250000
#define HD 64
#define NFD 16
#define CHUNK 1024
#define NCHUNK ((NODES + CHUNK - 1) / CHUNK)
#define BN_INV 0.9999950000374996f  // 1/sqrt(1+1e-5)
#define LP 65  // LDS row pitch: 65 % 32 == 1 -> 2-way bank aliasing (free)
#define SRCMASK 0x1FFFFu
#define WSCALE (1.0f / 32768.0f)

// ---------------- graph build ----------------

__global__ void k_hist(const int* __restrict__ ei, int* __restrict__ deg) {
  int e = blockIdx.x * blockDim.x + threadIdx.x;
  if (e < EDGES) atomicAdd(&deg[ei[EDGES + e]], 1);
}

__global__ void k_scan1(const int* __restrict__ deg, int* __restrict__ part) {
  __shared__ int lds[256];
  int t = threadIdx.x, b = blockIdx.x;
  int base = b * CHUNK + t * 4;
  int s = 0;
#pragma unroll
  for (int m = 0; m < 4; m++) { int i = base + m; if (i < NODES) s += deg[i]; }
  lds[t] = s; __syncthreads();
  for (int off = 128; off > 0; off >>= 1) {
    if (t < off) lds[t] += lds[t + off];
    __syncthreads();
  }
  if (t == 0) part[b] = lds[0];
}

__global__ void k_scan2(int* __restrict__ part) {
  if (threadIdx.x == 0 && blockIdx.x == 0) {
    int run = 0;
    for (int c = 0; c < NCHUNK; c++) { int v = part[c]; part[c] = run; run += v; }
  }
}

__global__ void k_scan3(const int* __restrict__ deg, const int* __restrict__ part,
                        int* __restrict__ rowptr, int* __restrict__ cur,
                        float* __restrict__ dis) {
  __shared__ int lds[256];
  int t = threadIdx.x, b = blockIdx.x;
  int base = b * CHUNK + t * 4;
  int dl[4]; int s = 0;
#pragma unroll
  for (int m = 0; m < 4; m++) { int i = base + m; dl[m] = (i < NODES) ? deg[i] : 0; s += dl[m]; }
  lds[t] = s; __syncthreads();
  for (int off = 1; off < 256; off <<= 1) {
    int add = (t >= off) ? lds[t - off] : 0;
    __syncthreads();
    lds[t] += add;
    __syncthreads();
  }
  int run = part[b] + lds[t] - s;  // exclusive prefix for this thread
#pragma unroll
  for (int m = 0; m < 4; m++) {
    int i = base + m;
    if (i < NODES) {
      rowptr[i] = run; cur[i] = run;
      dis[i] = 1.0f / sqrtf((float)(dl[m] + 1));  // GCN: indeg + self-loop
    }
    run += dl[m];
  }
  if (b == 0 && t == 0) rowptr[NODES] = EDGES;
}

// attention coeff in ORIGINAL edge order; packed 4B scatter: (q15(a)<<17)|src
__global__ void k_fillatt(const int* __restrict__ ei, const float* __restrict__ ea,
                          const float* __restrict__ cvec, const float* __restrict__ dvec,
                          const float* __restrict__ Wa, const float* __restrict__ ba,
                          int* __restrict__ cur, uint* __restrict__ sa) {
  int e = blockIdx.x * blockDim.x + threadIdx.x;
  if (e >= EDGES) return;
  int s = ei[e], d = ei[EDGES + e];
  float alin = cvec[d] + dvec[s] + ea[3 * e] * Wa[128] + ea[3 * e + 1] * Wa[129] +
               ea[3 * e + 2] * Wa[130] + ba[0];
  float lr = alin >= 0.f ? alin : 0.01f * alin;
  float a = 1.f / (1.f + expf(-lr));
  uint q = min((int)(a * 32768.f + 0.5f), 32767);
  int p = atomicAdd(&cur[d], 1);
  sa[p] = (q << 17) | (uint)s;
}

// ---------------- fp16 helpers ----------------

__device__ __forceinline__ void store16h(__half* dst, const float* v) {
  uint u[8];
#pragma unroll
  for (int j = 0; j < 8; j++) {
    __half2 h = __float22half2_rn(make_float2(v[2 * j], v[2 * j + 1]));
    u[j] = *reinterpret_cast<uint*>(&h);
  }
  uint4* o = (uint4*)dst;
  o[0] = make_uint4(u[0], u[1], u[2], u[3]);
  o[1] = make_uint4(u[4], u[5], u[6], u[7]);
}

__device__ __forceinline__ float4 h4tof4(uint2 u) {
  float2 fa = __half22float2(*reinterpret_cast<__half2*>(&u.x));
  float2 fb = __half22float2(*reinterpret_cast<__half2*>(&u.y));
  return make_float4(fa.x, fa.y, fb.x, fb.y);
}

// one 16-edge gather step (4 edge slots x 16 col-lanes), fp16 rows, packed sa
__device__ __forceinline__ void gstep(const __half* __restrict__ tab,
                                      const uint* __restrict__ sa,
                                      int m, int end, int last, int sub, int col,
                                      bool weighted,
                                      float4& A0, float4& A1, float4& A2, float4& A3) {
  int e0 = m + sub, e1 = e0 + 4, e2 = e0 + 8, e3 = e0 + 12;
  uint s0 = sa[min(e0, last)], s1 = sa[min(e1, last)];
  uint s2 = sa[min(e2, last)], s3 = sa[min(e3, last)];
  float w0 = (e0 < end) ? (weighted ? (float)(s0 >> 17) * WSCALE : 1.f) : 0.f;
  float w1 = (e1 < end) ? (weighted ? (float)(s1 >> 17) * WSCALE : 1.f) : 0.f;
  float w2 = (e2 < end) ? (weighted ? (float)(s2 >> 17) * WSCALE : 1.f) : 0.f;
  float w3 = (e3 < end) ? (weighted ? (float)(s3 >> 17) * WSCALE : 1.f) : 0.f;
  uint2 u0 = *((const uint2*)(tab + (size_t)(s0 & SRCMASK) * HD) + col);
  uint2 u1 = *((const uint2*)(tab + (size_t)(s1 & SRCMASK) * HD) + col);
  uint2 u2 = *((const uint2*)(tab + (size_t)(s2 & SRCMASK) * HD) + col);
  uint2 u3 = *((const uint2*)(tab + (size_t)(s3 & SRCMASK) * HD) + col);
  {
    float4 f = h4tof4(u0);
    A0.x = fmaf(w0, f.x, A0.x); A0.y = fmaf(w0, f.y, A0.y);
    A0.z = fmaf(w0, f.z, A0.z); A0.w = fmaf(w0, f.w, A0.w);
  }
  {
    float4 f = h4tof4(u1);
    A1.x = fmaf(w1, f.x, A1.x); A1.y = fmaf(w1, f.y, A1.y);
    A1.z = fmaf(w1, f.z, A1.z); A1.w = fmaf(w1, f.w, A1.w);
  }
  {
    float4 f = h4tof4(u2);
    A2.x = fmaf(w2, f.x, A2.x); A2.y = fmaf(w2, f.y, A2.y);
    A2.z = fmaf(w2, f.z, A2.z); A2.w = fmaf(w2, f.w, A2.w);
  }
  {
    float4 f = h4tof4(u3);
    A3.x = fmaf(w3, f.x, A3.x); A3.y = fmaf(w3, f.y, A3.y);
    A3.z = fmaf(w3, f.z, A3.z); A3.w = fmaf(w3, f.w, A3.w);
  }
}

__device__ __forceinline__ float4 red4(float4 a0, float4 a1, float4 a2, float4 a3) {
  float4 r;
  r.x = (a0.x + a1.x) + (a2.x + a3.x);
  r.y = (a0.y + a1.y) + (a2.y + a3.y);
  r.z = (a0.z + a1.z) + (a2.z + a3.z);
  r.w = (a0.w + a1.w) + (a2.w + a3.w);
#pragma unroll
  for (int off = 16; off <= 32; off <<= 1) {
    r.x += __shfl_xor(r.x, off); r.y += __shfl_xor(r.y, off);
    r.z += __shfl_xor(r.z, off); r.w += __shfl_xor(r.w, off);
  }
  return r;
}

#define AGG_BODY16(TABLE, WEIGHTED)                                              \
  float4 acc0 = make_float4(0.f, 0.f, 0.f, 0.f);                                 \
  float4 acc1 = make_float4(0.f, 0.f, 0.f, 0.f);                                 \
  float4 acc2 = make_float4(0.f, 0.f, 0.f, 0.f);                                 \
  float4 acc3 = make_float4(0.f, 0.f, 0.f, 0.f);                                 \
  int last = end - 1;                                                            \
  for (int m = start; m < end; m += 16)                                          \
    gstep(TABLE, sa, m, end, last, sub, col, WEIGHTED, acc0, acc1, acc2, acc3);  \
  float4 accr = red4(acc0, acc1, acc2, acc3);

// ---------------- kernels ----------------

// lin0: h = x@Wn + bn -> hI16, LDS ; h0 = h@Wl + bl -> hB16 ; cvec/dvec dots
__global__ __launch_bounds__(256) void k_lin0(
    const float* __restrict__ x,
    const float* __restrict__ Wn, const float* __restrict__ bn,
    const float* __restrict__ Wl, const float* __restrict__ bl,
    const float* __restrict__ Wa,
    __half* __restrict__ hI16, __half* __restrict__ hB16,
    float* __restrict__ cvec, float* __restrict__ dvec) {
  __shared__ float sh[64 * LP];
  __shared__ float sc[4][64], sd[4][64];
  int slot = threadIdx.x & 63;
  int cc = __builtin_amdgcn_readfirstlane(threadIdx.x >> 6);
  int c0 = cc * 16;
  int n0 = blockIdx.x * 64 + slot;
  bool valid = n0 < NODES;
  int n = valid ? n0 : NODES - 1;
  const float4* xr = (const float4*)(x + (size_t)n * NFD);
  float acc[16];
#pragma unroll
  for (int j = 0; j < 16; j++) acc[j] = bn[c0 + j];
#pragma unroll
  for (int q = 0; q < 4; q++) {
    float4 xa = xr[q];
    float xs[4] = {xa.x, xa.y, xa.z, xa.w};
#pragma unroll
    for (int t = 0; t < 4; t++)
#pragma unroll
      for (int j = 0; j < 16; j++)
        acc[j] = fmaf(xs[t], Wn[(q * 4 + t) * HD + c0 + j], acc[j]);
  }
#pragma unroll
  for (int j = 0; j < 16; j++) sh[slot * LP + c0 + j] = acc[j];
  if (valid) store16h(hI16 + (size_t)n * HD + c0, acc);
  __syncthreads();
  float a2[16];
#pragma unroll
  for (int j = 0; j < 16; j++) a2[j] = bl[c0 + j];
#pragma unroll 8
  for (int k = 0; k < 64; k++) {
    float hk = sh[slot * LP + k];
#pragma unroll
    for (int j = 0; j < 16; j++)
      a2[j] = fmaf(hk, Wl[k * HD + c0 + j], a2[j]);
  }
  float cn = 0.f, dn = 0.f;
#pragma unroll
  for (int j = 0; j < 16; j++) {
    cn = fmaf(a2[j], Wa[c0 + j], cn);
    dn = fmaf(a2[j], Wa[64 + c0 + j], dn);
  }
  if (valid) store16h(hB16 + (size_t)n * HD + c0, a2);
  sc[cc][slot] = cn;
  sd[cc][slot] = dn;
  __syncthreads();
  if (cc == 0 && valid) {
    cvec[n] = sc[0][slot] + sc[1][slot] + sc[2][slot] + sc[3][slot];
    dvec[n] = sd[0][slot] + sd[1][slot] + sd[2][slot] + sd[3][slot];
  }
}

// layer0 aggregation: gather hB16 (weighted), ident from hI16 -> hC16 only
__global__ __launch_bounds__(256) void k_agg_att(
    const uint* __restrict__ sa, const int* __restrict__ rowptr,
    const __half* __restrict__ hI16, const __half* __restrict__ hB16,
    const float* __restrict__ g, const float* __restrict__ bt,
    __half* __restrict__ hC16) {
  int lane = threadIdx.x & 63;
  int node = __builtin_amdgcn_readfirstlane(blockIdx.x * 4 + (threadIdx.x >> 6));
  if (node >= NODES) return;
  int start = rowptr[node], end = rowptr[node + 1];
  int sub = lane >> 4, col = lane & 15;
  float4 gg = ((const float4*)g)[col];
  float4 bb = ((const float4*)bt)[col];
  float4 ha = h4tof4(*((const uint2*)(hI16 + (size_t)node * HD) + col));
  AGG_BODY16(hB16, true)
  if (lane < 16) {
    float4 v;
    v.x = fmaxf(accr.x * (gg.x * BN_INV) + bb.x, 0.f) + ha.x;
    v.y = fmaxf(accr.y * (gg.y * BN_INV) + bb.y, 0.f) + ha.y;
    v.z = fmaxf(accr.z * (gg.z * BN_INV) + bb.z, 0.f) + ha.z;
    v.w = fmaxf(accr.w * (gg.w * BN_INV) + bb.w, 0.f) + ha.w;
    __half2 p0 = __float22half2_rn(make_float2(v.x, v.y));
    __half2 p1 = __float22half2_rn(make_float2(v.z, v.w));
    uint2 u;
    u.x = *reinterpret_cast<uint*>(&p0);
    u.y = *reinterpret_cast<uint*>(&p1);
    *((uint2*)(hC16 + (size_t)node * HD) + col) = u;
  }
}

// mean aggregation, wave-per-node: gather hC16 -> fp16 mean rows (hM16)
__global__ __launch_bounds__(256) void k_agg_mean16(
    const uint* __restrict__ sa, const int* __restrict__ rowptr,
    const __half* __restrict__ hC16, __half* __restrict__ hM16) {
  int lane = threadIdx.x & 63;
  int node = __builtin_amdgcn_readfirstlane(blockIdx.x * 4 + (threadIdx.x >> 6));
  if (node >= NODES) return;
  int start = rowptr[node], end = rowptr[node + 1];
  int sub = lane >> 4, col = lane & 15;
  AGG_BODY16(hC16, false)
  if (lane < 16) {
    float rdeg = 1.f / fmaxf((float)(end - start), 1.f);
    __half2 p0 = __float22half2_rn(make_float2(accr.x * rdeg, accr.y * rdeg));
    __half2 p1 = __float22half2_rn(make_float2(accr.z * rdeg, accr.w * rdeg));
    uint2 u;
    u.x = *reinterpret_cast<uint*>(&p0);
    u.y = *reinterpret_cast<uint*>(&p1);
    *((uint2*)(hM16 + (size_t)node * HD) + col) = u;
  }
}

// SAGE + GCN pre-GEMM (GEMM-only tile kernel), all-fp16 row inputs:
// t = relu(BN1(hM@Wsl + hC@Wsr + bsl)) + hC -> hT16 ; hD16 = dis*(t@Wg)
__global__ __launch_bounds__(256) void k_sagegcn(
    const __half* __restrict__ hM16, const __half* __restrict__ hC16,
    const float* __restrict__ Wl, const float* __restrict__ bl,
    const float* __restrict__ Wr, const float* __restrict__ Wg,
    const float* __restrict__ g, const float* __restrict__ bt,
    const float* __restrict__ dis,
    __half* __restrict__ hT16, __half* __restrict__ hD16) {
  __shared__ float sh[64 * LP];
  int slot = threadIdx.x & 63;
  int cc = __builtin_amdgcn_readfirstlane(threadIdx.x >> 6);
  int c0 = cc * 16;
  int n0 = blockIdx.x * 64 + slot;
  bool valid = n0 < NODES;
  int n = valid ? n0 : NODES - 1;
  // stage mean row chunk (16 halves) into LDS as fp32
  {
    const uint4* mp = (const uint4*)(hM16 + (size_t)n * HD + c0);
    uint4 m0 = mp[0], m1 = mp[1];
    uint mm[8] = {m0.x, m0.y, m0.z, m0.w, m1.x, m1.y, m1.z, m1.w};
#pragma unroll
    for (int j = 0; j < 8; j++) {
      float2 f = __half22float2(*reinterpret_cast<__half2*>(&mm[j]));
      sh[slot * LP + c0 + 2 * j] = f.x;
      sh[slot * LP + c0 + 2 * j + 1] = f.y;
    }
  }
  __syncthreads();
  // load full fp16 hC row (64 halves = 8 x uint4)
  uint4 cu[8];
  {
    const uint4* cp = (const uint4*)(hC16 + (size_t)n * HD);
#pragma unroll
    for (int q = 0; q < 8; q++) cu[q] = cp[q];
  }
  float acc[16];
#pragma unroll
  for (int j = 0; j < 16; j++) acc[j] = bl[c0 + j];
#pragma unroll 8
  for (int k = 0; k < 64; k++) {
    float mk = sh[slot * LP + k];
#pragma unroll
    for (int j = 0; j < 16; j++)
      acc[j] = fmaf(mk, Wl[k * HD + c0 + j], acc[j]);
  }
  // Wr GEMM from in-register fp16 row
#pragma unroll
  for (int q = 0; q < 8; q++) {
    uint uw[4] = {cu[q].x, cu[q].y, cu[q].z, cu[q].w};
#pragma unroll
    for (int t = 0; t < 4; t++) {
      float2 f = __half22float2(*reinterpret_cast<__half2*>(&uw[t]));
      int k = q * 8 + t * 2;
#pragma unroll
      for (int j = 0; j < 16; j++)
        acc[j] = fmaf(f.x, Wr[k * HD + c0 + j], acc[j]);
#pragma unroll
      for (int j = 0; j < 16; j++)
        acc[j] = fmaf(f.y, Wr[(k + 1) * HD + c0 + j], acc[j]);
    }
  }
  // residual chunk from the same registers
  float tv[16];
  {
    uint uw0[4] = {cu[cc * 2].x, cu[cc * 2].y, cu[cc * 2].z, cu[cc * 2].w};
    uint uw1[4] = {cu[cc * 2 + 1].x, cu[cc * 2 + 1].y, cu[cc * 2 + 1].z, cu[cc * 2 + 1].w};
    float rv[16];
#pragma unroll
    for (int t = 0; t < 4; t++) {
      float2 f = __half22float2(*reinterpret_cast<__half2*>(&uw0[t]));
      rv[2 * t] = f.x; rv[2 * t + 1] = f.y;
    }
#pragma unroll
    for (int t = 0; t < 4; t++) {
      float2 f = __half22float2(*reinterpret_cast<__half2*>(&uw1[t]));
      rv[8 + 2 * t] = f.x; rv[8 + 2 * t + 1] = f.y;
    }
#pragma unroll
    for (int j = 0; j < 16; j++)
      tv[j] = fmaxf(acc[j] * (g[c0 + j] * BN_INV) + bt[c0 + j], 0.f) + rv[j];
  }
  __syncthreads();  // mean rows fully consumed -> safe to overwrite
#pragma unroll
  for (int j = 0; j < 16; j++) sh[slot * LP + c0 + j] = tv[j];
  if (valid) store16h(hT16 + (size_t)n * HD + c0, tv);
  __syncthreads();
  float di = dis[n];
  float a2[16];
#pragma unroll
  for (int j = 0; j < 16; j++) a2[j] = 0.f;
#pragma unroll 8
  for (int k = 0; k < 64; k++) {
    float tk = sh[slot * LP + k];
#pragma unroll
    for (int j = 0; j < 16; j++)
      a2[j] = fmaf(tk, Wg[k * HD + c0 + j], a2[j]);
  }
#pragma unroll
  for (int j = 0; j < 16; j++) a2[j] *= di;
  if (valid) store16h(hD16 + (size_t)n * HD + c0, a2);
}

// GCN aggregation, wave-per-node: gather hD16 + full layer2 epilogue -> hO16
__global__ __launch_bounds__(256) void k_agg_gcn16(
    const uint* __restrict__ sa, const int* __restrict__ rowptr,
    const float* __restrict__ dis,
    const __half* __restrict__ hT16,  // t (residual ident, fp16)
    const __half* __restrict__ hD16,  // fp16 gather + self table
    const float* __restrict__ bg,
    const float* __restrict__ g, const float* __restrict__ bt,
    __half* __restrict__ hO16) {
  int lane = threadIdx.x & 63;
  int node = __builtin_amdgcn_readfirstlane(blockIdx.x * 4 + (threadIdx.x >> 6));
  if (node >= NODES) return;
  int start = rowptr[node], end = rowptr[node + 1];
  int sub = lane >> 4, col = lane & 15;
  float di = dis[node];
  float4 sv = h4tof4(*((const uint2*)(hD16 + (size_t)node * HD) + col));  // self
  float4 ha = h4tof4(*((const uint2*)(hT16 + (size_t)node * HD) + col));
  float4 gg = ((const float4*)g)[col];
  float4 bb = ((const float4*)bt)[col];
  float4 bgv = ((const float4*)bg)[col];
  AGG_BODY16(hD16, false)
  if (lane < 16) {
    float4 v;
    v.x = fmaxf((di * (accr.x + sv.x) + bgv.x) * (gg.x * BN_INV) + bb.x, 0.f) + ha.x;
    v.y = fmaxf((di * (accr.y + sv.y) + bgv.y) * (gg.y * BN_INV) + bb.y, 0.f) + ha.y;
    v.z = fmaxf((di * (accr.z + sv.z) + bgv.z) * (gg.z * BN_INV) + bb.z, 0.f) + ha.z;
    v.w = fmaxf((di * (accr.w + sv.w) + bgv.w) * (gg.w * BN_INV) + bb.w, 0.f) + ha.w;
    __half2 p0 = __float22half2_rn(make_float2(v.x, v.y));
    __half2 p1 = __float22half2_rn(make_float2(v.z, v.w));
    uint2 u;
    u.x = *reinterpret_cast<uint*>(&p0);
    u.y = *reinterpret_cast<uint*>(&p1);
    *((uint2*)(hO16 + (size_t)node * HD) + col) = u;
  }
}

// regressor head (GEMM-only tile kernel): out = relu(relu(hO@W1+b1)@W2+b2)@W3+b3
__global__ __launch_bounds__(256) void k_reg(
    const __half* __restrict__ hO16,
    const float* __restrict__ W1, const float* __restrict__ b1,
    const float* __restrict__ W2, const float* __restrict__ b2,
    const float* __restrict__ W3, const float* __restrict__ b3,
    float* __restrict__ out) {
  __shared__ float sh[64 * LP];
  __shared__ float sred[4][64];
  int slot = threadIdx.x & 63;
  int cc = __builtin_amdgcn_readfirstlane(threadIdx.x >> 6);
  int c0 = cc * 16;
  int n0 = blockIdx.x * 64 + slot;
  bool valid = n0 < NODES;
  int n = valid ? n0 : NODES - 1;
  // stage fp16 row chunk into LDS as fp32
  {
    const uint4* mp = (const uint4*)(hO16 + (size_t)n * HD + c0);
    uint4 m0 = mp[0], m1 = mp[1];
    uint mm[8] = {m0.x, m0.y, m0.z, m0.w, m1.x, m1.y, m1.z, m1.w};
#pragma unroll
    for (int j = 0; j < 8; j++) {
      float2 f = __half22float2(*reinterpret_cast<__half2*>(&mm[j]));
      sh[slot * LP + c0 + 2 * j] = f.x;
      sh[slot * LP + c0 + 2 * j + 1] = f.y;
    }
  }
  __syncthreads();
  float acc[16];
#pragma unroll
  for (int j = 0; j < 16; j++) acc[j] = b1[c0 + j];
#pragma unroll 8
  for (int k = 0; k < 64; k++) {
    float rk = sh[slot * LP + k];
#pragma unroll
    for (int j = 0; j < 16; j++)
      acc[j] = fmaf(rk, W1[k * HD + c0 + j], acc[j]);
  }
  float t1v[16];
#pragma unroll
  for (int j = 0; j < 16; j++) t1v[j] = fmaxf(acc[j], 0.f);
  __syncthreads();  // input rows consumed -> overwrite with t1
#pragma unroll
  for (int j = 0; j < 16; j++) sh[slot * LP + c0 + j] = t1v[j];
  __syncthreads();
  int d0 = cc * 8;
  float a2[8];
#pragma unroll
  for (int j = 0; j < 8; j++) a2[j] = b2[d0 + j];
#pragma unroll 8
  for (int k = 0; k < 64; k++) {
    float tk = sh[slot * LP + k];
#pragma unroll
    for (int j = 0; j < 8; j++)
      a2[j] = fmaf(tk, W2[k * 32 + d0 + j], a2[j]);
  }
  float part = 0.f;
#pragma unroll
  for (int j = 0; j < 8; j++) part = fmaf(fmaxf(a2[j], 0.f), W3[d0 + j], part);
  sred[cc][slot] = part;
  __syncthreads();
  if (cc == 0 && valid)
    out[n] = sred[0][slot] + sred[1][slot] + sred[2][slot] + sred[3][slot] + b3[0];
}

// ---------------- host launch ----------------

extern "C" void kernel_launch(void* const* d_in, const int* in_sizes, int n_in,
                              void* d_out, int out_size, void* d_ws, size_t ws_size,
                              hipStream_t stream) {
  const float* x      = (const float*)d_in[0];
  const float* ea     = (const float*)d_in[1];
  const int*   ei     = (const int*)d_in[2];
  const float* W_node = (const float*)d_in[3];
  const float* b_node = (const float*)d_in[4];
  // d_in[5], d_in[6]: W_edge/b_edge — unused by the reference output
  const float* W_lin0 = (const float*)d_in[7];
  const float* b_lin0 = (const float*)d_in[8];
  const float* W_att0 = (const float*)d_in[9];
  const float* b_att0 = (const float*)d_in[10];
  const float* W_sl   = (const float*)d_in[11];
  const float* b_sl   = (const float*)d_in[12];
  const float* W_sr   = (const float*)d_in[13];
  const float* W_gcn  = (const float*)d_in[14];
  const float* b_gcn  = (const float*)d_in[15];
  const float* bn_g   = (const float*)d_in[16];  // [3,64]
  const float* bn_b   = (const float*)d_in[17];
  const float* W_r1   = (const float*)d_in[18];
  const float* b_r1   = (const float*)d_in[19];
  const float* W_r2   = (const float*)d_in[20];
  const float* b_r2   = (const float*)d_in[21];
  const float* W_r3   = (const float*)d_in[22];
  const float* b_r3   = (const float*)d_in[23];
  float* out = (float*)d_out;

  char* ws = (char*)d_ws;
  size_t o = 0;
  auto alloc = [&](size_t bytes) -> void* {
    void* p = ws + o;
    o += (bytes + 255) & ~(size_t)255;
    return p;
  };
  int*    deg    = (int*)alloc(NODES * 4);
  int*    rowptr = (int*)alloc((NODES + 1) * 4);
  int*    cur    = (int*)alloc(NODES * 4);
  int*    part   = (int*)alloc(256 * 4);
  uint*   sa     = (uint*)alloc((size_t)EDGES * 4);
  __half* hI16   = (__half*)alloc((size_t)NODES * HD * 2);  // h ident
  __half* hB16   = (__half*)alloc((size_t)NODES * HD * 2);  // h0, then hM16
  __half* hC16   = (__half*)alloc((size_t)NODES * HD * 2);  // hC, then hO16
  __half* hT16   = (__half*)alloc((size_t)NODES * HD * 2);  // t
  __half* hD16   = (__half*)alloc((size_t)NODES * HD * 2);
  float*  cvec   = (float*)alloc(NODES * 4);
  float*  dvec   = (float*)alloc(NODES * 4);
  float*  dis    = (float*)alloc(NODES * 4);
  (void)ws_size; (void)in_sizes; (void)n_in; (void)out_size;

  const int EB  = (EDGES + 255) / 256;
  const int NT  = (NODES + 63) / 64;     // 64 nodes/block
  const int NBW = (NODES + 3) / 4;       // wave-per-node (4 waves/block)

  hipMemsetAsync(deg, 0, NODES * 4, stream);
  k_hist<<<EB, 256, 0, stream>>>(ei, deg);
  k_scan1<<<NCHUNK, 256, 0, stream>>>(deg, part);
  k_scan2<<<1, 64, 0, stream>>>(part);
  k_scan3<<<NCHUNK, 256, 0, stream>>>(deg, part, rowptr, cur, dis);

  k_lin0<<<NT, 256, 0, stream>>>(x, W_node, b_node, W_lin0, b_lin0, W_att0,
                                 hI16, hB16, cvec, dvec);
  k_fillatt<<<EB, 256, 0, stream>>>(ei, ea, cvec, dvec, W_att0, b_att0, cur, sa);
  k_agg_att<<<NBW, 256, 0, stream>>>(sa, rowptr, hI16, hB16,
                                     bn_g + 0 * HD, bn_b + 0 * HD, hC16);
  // hB16 (h0) dead -> reuse as fp16 mean table
  k_agg_mean16<<<NBW, 256, 0, stream>>>(sa, rowptr, hC16, hB16);
  // GEMM-only SAGE + GCN pre-GEMM: t -> hT16, hBp -> hD16
  k_sagegcn<<<NT, 256, 0, stream>>>(hB16, hC16, W_sl, b_sl, W_sr, W_gcn,
                                    bn_g + 1 * HD, bn_b + 1 * HD, dis, hT16, hD16);
  // GCN aggregation (wave-per-node) -> layer2 rows into hC16 (dead)
  k_agg_gcn16<<<NBW, 256, 0, stream>>>(sa, rowptr, dis, hT16, hD16, b_gcn,
                                       bn_g + 2 * HD, bn_b + 2 * HD, hC16);
  // regressor head from fp16 rows -> out
  k_reg<<<NT, 256, 0, stream>>>(hC16, W_r1, b_r1, W_r2, b_r2, W_r3, b_r3, out);
}